// Round 11
// baseline (561.535 us; speedup 1.0000x reference)
//
#include <hip/hip_runtime.h>
#include <hip/hip_bf16.h>
#include <math.h>

#define NN 20000
#define NE 320000

typedef unsigned short ushort_t;
typedef unsigned short ushortx8 __attribute__((ext_vector_type(8)));
typedef short s16x8 __attribute__((ext_vector_type(8)));
typedef float f32x4 __attribute__((ext_vector_type(4)));
typedef float f32x2 __attribute__((ext_vector_type(2)));

__device__ __forceinline__ float us2f(unsigned short u){
  return __uint_as_float(((unsigned)u) << 16);
}
__device__ __forceinline__ unsigned short f2us(float f){
  unsigned u = __float_as_uint(f);
  unsigned r = (u + 0x7fffu + ((u >> 16) & 1u)) >> 16;   // RNE
  return (unsigned short)r;
}
__device__ __forceinline__ void e4m3x8_to_f32(uint2 d, float* out){
  f32x2 a = __builtin_amdgcn_cvt_pk_f32_fp8(d.x, false);
  f32x2 b = __builtin_amdgcn_cvt_pk_f32_fp8(d.x, true);
  f32x2 c = __builtin_amdgcn_cvt_pk_f32_fp8(d.y, false);
  f32x2 e = __builtin_amdgcn_cvt_pk_f32_fp8(d.y, true);
  out[0] = a.x; out[1] = a.y; out[2] = b.x; out[3] = b.y;
  out[4] = c.x; out[5] = c.y; out[6] = e.x; out[7] = e.y;
}
__device__ __forceinline__ uint2 f32x8_to_e4m3(const float* f){
  unsigned lo = __builtin_amdgcn_cvt_pk_fp8_f32(f[0], f[1], 0u, false);
  lo = __builtin_amdgcn_cvt_pk_fp8_f32(f[2], f[3], lo, true);
  unsigned hi = __builtin_amdgcn_cvt_pk_fp8_f32(f[4], f[5], 0u, false);
  hi = __builtin_amdgcn_cvt_pk_fp8_f32(f[6], f[7], hi, true);
  return make_uint2(lo, hi);
}
// DPP butterfly add within 16-lane rows. Bit-identical to the shfl_xor chain.
template<int CTRL>
__device__ __forceinline__ float dpp_add(float x){
  int t = __builtin_amdgcn_update_dpp(0, __float_as_int(x), CTRL, 0xf, 0xf, true);
  return x + __int_as_float(t);
}
__device__ __forceinline__ float red16(float p){
  p = dpp_add<0xB1>(p);    // quad_perm [1,0,3,2]  == xor 1
  p = dpp_add<0x4E>(p);    // quad_perm [2,3,0,1]  == xor 2
  p = dpp_add<0x141>(p);   // row_half_mirror      == xor 4 (value-equal)
  p = dpp_add<0x140>(p);   // row_mirror           == xor 8 (value-equal)
  return p;
}

// ---------------- CSR build ----------------
__global__ void k_hist(const int* __restrict__ ei, int* __restrict__ deg){
  int e = blockIdx.x * 256 + threadIdx.x;
  if (e < NE) atomicAdd(&deg[ei[NE + e]], 1);
}

__global__ __launch_bounds__(1024) void k_scan(const int* __restrict__ deg,
                                               int* __restrict__ rowst,
                                               int* __restrict__ cur){
  __shared__ int ws[16];
  int tid = threadIdx.x;
  int lane = tid & 63, wid = tid >> 6;
  int base = tid * 20;
  int v[20];
  int s = 0;
  #pragma unroll
  for (int u = 0; u < 20; u++){
    int i = base + u;
    int d = (i < NN) ? deg[i] : 0;
    v[u] = s;
    s += d;
  }
  int incl = s;
  #pragma unroll
  for (int off = 1; off < 64; off <<= 1){
    int t = __shfl_up(incl, off);
    if (lane >= off) incl += t;
  }
  if (lane == 63) ws[wid] = incl;
  __syncthreads();
  int woff = 0;
  #pragma unroll
  for (int k2 = 0; k2 < 16; k2++) if (k2 < wid) woff += ws[k2];
  int toff = woff + incl - s;
  #pragma unroll
  for (int u = 0; u < 20; u++){
    int i = base + u;
    if (i < NN){ int e = toff + v[u]; rowst[i] = e; cur[i] = e; }
  }
  if (tid == 1023) rowst[NN] = toff + s;
}

__global__ void k_scatter(const int* __restrict__ ei, int* __restrict__ cur,
                          int* __restrict__ srcs){
  int e = blockIdx.x * 256 + threadIdx.x;
  if (e < NE){
    int s = ei[e];
    int d = ei[NE + e];
    int p = atomicAdd(&cur[d], 1);
    srcs[p] = s;
  }
}

// ---- degree-bucket permutation: perm groups nodes of equal degree ----
__global__ void k_dhist(const int* __restrict__ deg, int* __restrict__ dcnt){
  int n = blockIdx.x * 256 + threadIdx.x;
  if (n < NN){
    int d = deg[n]; if (d > 127) d = 127;
    atomicAdd(&dcnt[d], 1);
  }
}
__global__ __launch_bounds__(64) void k_dscan(const int* __restrict__ dcnt,
                                              int* __restrict__ dcur){
  int lane = threadIdx.x;
  int v0 = dcnt[lane * 2], v1 = dcnt[lane * 2 + 1];
  int s = v0 + v1;
  int incl = s;
  #pragma unroll
  for (int off = 1; off < 64; off <<= 1){
    int t = __shfl_up(incl, off);
    if (lane >= off) incl += t;
  }
  int excl = incl - s;
  dcur[lane * 2] = excl;
  dcur[lane * 2 + 1] = excl + v0;
}
__global__ void k_dscatter(const int* __restrict__ deg, int* __restrict__ dcur,
                           int* __restrict__ perm){
  int n = blockIdx.x * 256 + threadIdx.x;
  if (n < NN){
    int d = deg[n]; if (d > 127) d = 127;
    int p = atomicAdd(&dcur[d], 1);
    perm[p] = n;
  }
}

// ------- weight convert+transpose + bias concat + deg/dcnt zero (one kernel) -------
__global__ void k_wt(const float* __restrict__ Wq, const float* __restrict__ Wk,
                     const float* __restrict__ Wv, const float* __restrict__ Wsk,
                     const float* __restrict__ W1, const float* __restrict__ W2,
                     const float* __restrict__ bq, const float* __restrict__ bk,
                     const float* __restrict__ bv, const float* __restrict__ bsk,
                     ushort_t* __restrict__ out, float* __restrict__ bcat,
                     int* __restrict__ deg){
  int f = blockIdx.x * 256 + threadIdx.x;
  if (f < 688128){
    float val;
    if (f < 425984){
      int l = f / 212992, idx = f % 212992;
      int n = idx / 128, kk = idx % 128;
      if (n < 512)       val = Wq[(size_t)l * 65536 + kk * 512 + n];
      else if (n < 1024) val = Wk[(size_t)l * 65536 + kk * 512 + (n - 512)];
      else if (n < 1536) val = Wv[(size_t)l * 65536 + kk * 512 + (n - 1024)];
      else               val = Wsk[(size_t)l * 16384 + kk * 128 + (n - 1536)];
    } else if (f < 557056){
      int idx = f - 425984;
      int l = idx / 65536, r = idx % 65536;
      int n = r / 128, kk = r % 128;
      val = W1[(size_t)l * 65536 + kk * 512 + n];
    } else {
      int idx = f - 557056;
      int l = idx / 65536, r = idx % 65536;
      int n = r / 512, kk = r % 512;
      val = W2[(size_t)l * 65536 + kk * 128 + n];
    }
    out[f] = f2us(val);
  } else if (f < 691456){
    int i = f - 688128;
    int l = i / 1664, c = i % 1664;
    float v;
    if (c < 512)       v = bq[l * 512 + c];
    else if (c < 1024) v = bk[l * 512 + c - 512];
    else if (c < 1536) v = bv[l * 512 + c - 1024];
    else               v = bsk[l * 128 + c - 1536];
    bcat[i] = v;
  } else if (f < 711584){
    deg[f - 691456] = 0;   // zeroes deg[20000] + dcnt[128] (contiguous)
  }
}

// ------- input projection: h = x@Win + b_in (16 rows/block) + fused ln1(l=0) -------
__global__ __launch_bounds__(128) void k_inproj(const float* __restrict__ x,
                                                const float* __restrict__ Win,
                                                const float* __restrict__ bin,
                                                float* __restrict__ h,
                                                const float* __restrict__ sc,
                                                const float* __restrict__ bi,
                                                ushort_t* __restrict__ hn){
  __shared__ float sW[32 * 128];
  __shared__ float sx[16][32];
  int tid = threadIdx.x;
  for (int i = 0; i < 32; i++) sW[i * 128 + tid] = Win[i * 128 + tid];
  int r0 = blockIdx.x * 16;
  for (int rr = tid >> 5; rr < 16; rr += 4){
    int gr = r0 + rr;
    sx[rr][tid & 31] = (gr < NN) ? x[(size_t)gr * 32 + (tid & 31)] : 0.f;
  }
  __syncthreads();
  float bias = bin[tid];
  for (int r = 0; r < 16; r++){
    int gr = r0 + r;
    if (gr >= NN) break;
    float acc = bias;
    #pragma unroll
    for (int k2 = 0; k2 < 32; k2++) acc += sx[r][k2] * sW[k2 * 128 + tid];
    h[(size_t)gr * 128 + tid] = acc;
  }
  __threadfence_block();
  __syncthreads();
  int lane = tid & 63, wv = tid >> 6;
  for (int rr = 0; rr < 8; rr++){
    int r = wv * 8 + rr;
    int gr = r0 + r;
    if (gr >= NN) continue;
    const float* p = h + (size_t)gr * 128 + lane * 2;
    float x0 = p[0], x1 = p[1];
    float sum = x0 + x1;
    for (int m = 1; m < 64; m <<= 1) sum += __shfl_xor(sum, m);
    float mean = sum * (1.f / 128.f);
    float d0 = x0 - mean, d1 = x1 - mean;
    float vs = d0 * d0 + d1 * d1;
    for (int m = 1; m < 64; m <<= 1) vs += __shfl_xor(vs, m);
    float rstd = rsqrtf(vs * (1.f / 128.f) + 1e-5f);
    int d = lane * 2;
    ushort_t* o = hn + (size_t)gr * 128 + d;
    o[0] = f2us(d0 * rstd * sc[d] + bi[d]);
    o[1] = f2us(d1 * rstd * sc[d + 1] + bi[d + 1]);
  }
}

// ---------------- LayerNorm (wave per row); OUTBF16: write bf16 else fp32 ----------------
template<int OUTBF16>
__global__ void k_ln(const float* __restrict__ in, const float* __restrict__ sc,
                     const float* __restrict__ bi, void* __restrict__ outp, int rows){
  int row = blockIdx.x * 4 + (threadIdx.x >> 6);
  int lane = threadIdx.x & 63;
  if (row >= rows) return;
  const float* p = in + (size_t)row * 128 + lane * 2;
  float x0 = p[0], x1 = p[1];
  float sum = x0 + x1;
  for (int m = 1; m < 64; m <<= 1) sum += __shfl_xor(sum, m);
  float mean = sum * (1.f / 128.f);
  float d0 = x0 - mean, d1 = x1 - mean;
  float vs = d0 * d0 + d1 * d1;
  for (int m = 1; m < 64; m <<= 1) vs += __shfl_xor(vs, m);
  float rstd = rsqrtf(vs * (1.f / 128.f) + 1e-5f);
  int d = lane * 2;
  float o0 = d0 * rstd * sc[d] + bi[d];
  float o1 = d1 * rstd * sc[d + 1] + bi[d + 1];
  if (OUTBF16){
    ushort_t* o = (ushort_t*)outp + (size_t)row * 128 + d;
    o[0] = f2us(o0); o[1] = f2us(o1);
  } else {
    float* o = (float*)outp + (size_t)row * 128 + d;
    o[0] = o0; o[1] = o1;
  }
}

// ------- MFMA GEMM: C[M,N] = A[M,K](bf16) @ Bt[N,K](bf16)^T + bias -------
// MODE 1: gelu -> bf16 C (LDS epilogue)   MODE 2: C(f32) += g*(acc+bias) (direct)
// MODE 3: QKVS split -> q bf16 | kv fp8 interleaved (8B k | 8B v per 16B) | xr bf16
template<int MODE>
__global__ __launch_bounds__(256) void k_mm(const ushort_t* __restrict__ A, int M, int K,
                                            const ushort_t* __restrict__ Bt,
                                            const float* __restrict__ bias,
                                            void* __restrict__ Cp, int ldc,
                                            const float* __restrict__ gptr,
                                            ushort_t* __restrict__ qout,
                                            unsigned char* __restrict__ kvout,
                                            ushort_t* __restrict__ xrout,
                                            int nbn){
  __shared__ ushort_t smem[2 * 128 * 72];            // As | Bs, reused as Cs (128x136)
  ushort_t* As = smem;
  ushort_t* Bs = smem + 128 * 72;
  int tid = threadIdx.x;
  // bijective XCD swizzle, n fastest within each XCD chunk
  int nwg = gridDim.x;
  int orig = blockIdx.x;
  int q8 = nwg >> 3, r8 = nwg & 7;
  int xcd = orig & 7, jj = orig >> 3;
  int wgid = (xcd < r8) ? (xcd * (q8 + 1) + jj)
                        : (r8 * (q8 + 1) + (xcd - r8) * q8 + jj);
  int m0 = (wgid / nbn) * 128, n0 = (wgid % nbn) * 128;
  int lane = tid & 63, w = tid >> 6;
  int wm = (w >> 1) * 64, wn = (w & 1) * 64;
  int fr = lane & 15, fq = lane >> 4;
  f32x4 acc[4][4];
  #pragma unroll
  for (int i = 0; i < 4; i++)
    #pragma unroll
    for (int j = 0; j < 4; j++) acc[i][j] = (f32x4){0.f, 0.f, 0.f, 0.f};

  for (int k0 = 0; k0 < K; k0 += 64){
    __syncthreads();
    #pragma unroll
    for (int it = 0; it < 4; it++){
      int idx = it * 256 + tid;
      int row = idx >> 3, ks = (idx & 7) * 8;
      int gr = m0 + row; if (gr >= M) gr = M - 1;
      *(ushortx8*)&As[row * 72 + ks] = *(const ushortx8*)(A + (size_t)gr * K + k0 + ks);
      *(ushortx8*)&Bs[row * 72 + ks] = *(const ushortx8*)(Bt + (size_t)(n0 + row) * K + k0 + ks);
    }
    __syncthreads();
    #pragma unroll
    for (int ks = 0; ks < 64; ks += 32){
      s16x8 a[4], b[4];
      #pragma unroll
      for (int i = 0; i < 4; i++)
        a[i] = *(const s16x8*)&As[(wm + i * 16 + fr) * 72 + ks + fq * 8];
      #pragma unroll
      for (int j = 0; j < 4; j++)
        b[j] = *(const s16x8*)&Bs[(wn + j * 16 + fr) * 72 + ks + fq * 8];
      #pragma unroll
      for (int i = 0; i < 4; i++)
        #pragma unroll
        for (int j = 0; j < 4; j++)
          acc[i][j] = __builtin_amdgcn_mfma_f32_16x16x32_bf16(a[i], b[j], acc[i][j], 0, 0, 0);
    }
  }

  if (MODE == 2){
    float g = *gptr;
    #pragma unroll
    for (int i = 0; i < 4; i++){
      int grb = m0 + wm + i * 16 + fq * 4;
      #pragma unroll
      for (int r = 0; r < 4; r++){
        int gr = grb + r;
        if (gr >= M) continue;
        #pragma unroll
        for (int j = 0; j < 4; j++){
          int gc = n0 + wn + j * 16 + fr;
          float c = acc[i][j][r] + bias[gc];
          ((float*)Cp)[(size_t)gr * ldc + gc] += g * c;
        }
      }
    }
    return;
  }

  // ---- LDS-staged epilogue: frags -> bf16 Cs[row][col] (stride 136) -> vector stores ----
  __syncthreads();
  ushort_t* Cs = smem;
  #pragma unroll
  for (int i = 0; i < 4; i++){
    int rowb = wm + i * 16 + fq * 4;
    #pragma unroll
    for (int j = 0; j < 4; j++){
      int col = wn + j * 16 + fr;
      float bv = bias[n0 + col];
      #pragma unroll
      for (int r = 0; r < 4; r++){
        float c = acc[i][j][r] + bv;
        if (MODE == 1) c = 0.5f * c * (1.f + erff(c * 0.70710678118654752f));
        Cs[(rowb + r) * 136 + col] = f2us(c);
      }
    }
  }
  __syncthreads();
  // region is uniform per block: boundaries (512,1024,1536) are multiples of 128
  #pragma unroll
  for (int it = 0; it < 8; it++){
    int idx = it * 256 + tid;
    int row = idx >> 4, seg = idx & 15;
    int gr = m0 + row;
    if (gr >= M) continue;
    ushortx8 cv = *(const ushortx8*)&Cs[row * 136 + seg * 8];
    int gc = n0 + seg * 8;
    if (MODE == 1){
      *(ushortx8*)((ushort_t*)Cp + (size_t)gr * ldc + gc) = cv;
    } else { // MODE 3
      if (n0 < 512){
        *(ushortx8*)(qout + (size_t)gr * 512 + gc) = cv;
      } else if (n0 < 1536){
        float fv[8];
        #pragma unroll
        for (int t = 0; t < 8; t++) fv[t] = us2f(cv[t]);
        uint2 pk = f32x8_to_e4m3(fv);
        if (n0 < 1024){
          *(uint2*)(kvout + (size_t)gr * 1024 + (size_t)((gc - 512) >> 3) * 16) = pk;
        } else {
          *(uint2*)(kvout + (size_t)gr * 1024 + (size_t)((gc - 1024) >> 3) * 16 + 8) = pk;
        }
      } else {
        *(ushortx8*)(xrout + (size_t)gr * 128 + (gc - 1536)) = cv;
      }
    }
  }
}

// ---- FUSED attention: 4 deg-sorted nodes/block (256 thr), 12/4/1 tiers, DPP reduce ----
#define EDGE_PROC(KVD) {                                                     \
    float kf[8]; e4m3x8_to_f32(make_uint2((KVD).x, (KVD).y), kf);            \
    float p = 0.f;                                                           \
    _Pragma("unroll")                                                        \
    for (int t = 0; t < 8; t++) p += qf[t] * kf[t];                          \
    p = red16(p);                                                            \
    float wgt = __expf(p * scale);                                           \
    float vf[8]; e4m3x8_to_f32(make_uint2((KVD).z, (KVD).w), vf);            \
    l += wgt;                                                                \
    _Pragma("unroll")                                                        \
    for (int t = 0; t < 8; t++) acc[t] += wgt * vf[t];                       \
  }

__global__ __launch_bounds__(256) void k_attn(
                       const ushort_t* __restrict__ q, const unsigned char* __restrict__ kv8,
                       const int* __restrict__ rowst, const int* __restrict__ srcs,
                       const int* __restrict__ perm,
                       const ushort_t* __restrict__ xr, const float* __restrict__ Wb,
                       const float* __restrict__ g1p, float* __restrict__ h,
                       const float* __restrict__ sc2, const float* __restrict__ bi2,
                       ushort_t* __restrict__ hn){
  int idx = blockIdx.x * 4 + (threadIdx.x >> 6);
  int lane = threadIdx.x & 63;
  if (idx >= NN) return;
  int n = perm[idx];                      // deg-sorted: block's 4 waves have equal deg
  int s0 = rowst[n], s1 = rowst[n + 1];
  int deg = s1 - s0;
  float qf[8];
  {
    ushortx8 qv = *((const ushortx8*)(q + (size_t)n * 512) + lane);
    #pragma unroll
    for (int t = 0; t < 8; t++) qf[t] = us2f(qv[t]);
  }
  const float scale = 0.08838834764831845f;
  const uint4* kvb = (const uint4*)kv8;   // 64 chunks of 16B per node record
  float l = 0.f;
  float acc[8] = {0.f, 0.f, 0.f, 0.f, 0.f, 0.f, 0.f, 0.f};
  for (int c0 = s0; c0 < s1; c0 += 64){
    int rem = s1 - c0; if (rem > 64) rem = 64;
    int se = (lane < rem) ? srcs[c0 + lane] : 0;
    int j = 0;
    for (; j + 12 <= rem; j += 12){
      uint4 kvd[12];
      #pragma unroll
      for (int u = 0; u < 12; u++){
        int sv = __builtin_amdgcn_readlane(se, j + u);   // SGPR -> scalar base
        kvd[u] = kvb[(size_t)sv * 64 + lane];
      }
      #pragma unroll
      for (int u = 0; u < 12; u++) EDGE_PROC(kvd[u]);
    }
    for (; j + 4 <= rem; j += 4){
      uint4 kvd[4];
      #pragma unroll
      for (int u = 0; u < 4; u++){
        int sv = __builtin_amdgcn_readlane(se, j + u);
        kvd[u] = kvb[(size_t)sv * 64 + lane];
      }
      #pragma unroll
      for (int u = 0; u < 4; u++) EDGE_PROC(kvd[u]);
    }
    for (; j < rem; j++){
      int sv0 = __builtin_amdgcn_readlane(se, j);
      uint4 kvd = kvb[(size_t)sv0 * 64 + lane];
      EDGE_PROC(kvd);
    }
  }
  float inv = deg ? (0.25f / l) : 0.f;   // head-mean folded; deg==0 -> out=0
  #pragma unroll
  for (int t = 0; t < 8; t++){
    float r = acc[t] * inv;
    r += __shfl_xor(r, 16); r += __shfl_xor(r, 32);
    acc[t] = r;
  }
  // ---- epilogue on lanes 0..15: beta gate + residual + ln2 ----
  if (lane < 16){
    int d = lane * 8;
    float xv[8];
    {
      ushortx8 xrv = *(const ushortx8*)(xr + (size_t)n * 128 + d);
      #pragma unroll
      for (int t = 0; t < 8; t++) xv[t] = us2f(xrv[t]);
    }
    float pp = 0.f;
    #pragma unroll
    for (int t = 0; t < 8; t++){
      float w0 = Wb[d + t], w1 = Wb[128 + d + t], w2 = Wb[256 + d + t];
      pp += acc[t] * (w0 + w2) + xv[t] * (w1 - w2);
    }
    pp = red16(pp);
    float beta = 1.f / (1.f + __expf(-pp));
    float g = *g1p;
    float* hp = h + (size_t)n * 128 + d;
    float hv[8];
    {
      float4 h0 = *(const float4*)(hp);
      float4 h1 = *(const float4*)(hp + 4);
      hv[0]=h0.x; hv[1]=h0.y; hv[2]=h0.z; hv[3]=h0.w;
      hv[4]=h1.x; hv[5]=h1.y; hv[6]=h1.z; hv[7]=h1.w;
    }
    #pragma unroll
    for (int t = 0; t < 8; t++)
      hv[t] += g * (beta * xv[t] + (1.f - beta) * acc[t]);
    float s = 0.f;
    #pragma unroll
    for (int t = 0; t < 8; t++) s += hv[t];
    s = red16(s);
    float mean = s * (1.f / 128.f);
    float vs = 0.f;
    #pragma unroll
    for (int t = 0; t < 8; t++){ float dd = hv[t] - mean; vs += dd * dd; }
    vs = red16(vs);
    float rstd = rsqrtf(vs * (1.f / 128.f) + 1e-5f);
    *(float4*)(hp) = make_float4(hv[0], hv[1], hv[2], hv[3]);
    *(float4*)(hp + 4) = make_float4(hv[4], hv[5], hv[6], hv[7]);
    ushortx8 hno;
    #pragma unroll
    for (int t = 0; t < 8; t++)
      hno[t] = f2us((hv[t] - mean) * rstd * sc2[d + t] + bi2[d + t]);
    *(ushortx8*)(hn + (size_t)n * 128 + d) = hno;
  }
}

extern "C" void kernel_launch(void* const* d_in, const int* in_sizes, int n_in,
                              void* d_out, int out_size, void* d_ws, size_t ws_size,
                              hipStream_t stream){
  const float* x    = (const float*)d_in[0];
  const int*   ei   = (const int*)d_in[1];
  const float* Win  = (const float*)d_in[2];
  const float* bin  = (const float*)d_in[3];
  const float* ln1s = (const float*)d_in[4];
  const float* ln1b = (const float*)d_in[5];
  const float* Wq   = (const float*)d_in[6];
  const float* bq   = (const float*)d_in[7];
  const float* Wk   = (const float*)d_in[8];
  const float* bk   = (const float*)d_in[9];
  const float* Wv   = (const float*)d_in[10];
  const float* bv   = (const float*)d_in[11];
  const float* Wsk  = (const float*)d_in[12];
  const float* bsk  = (const float*)d_in[13];
  const float* Wbt  = (const float*)d_in[14];
  const float* ln2s = (const float*)d_in[15];
  const float* ln2b = (const float*)d_in[16];
  const float* W1   = (const float*)d_in[17];
  const float* b1   = (const float*)d_in[18];
  const float* W2   = (const float*)d_in[19];
  const float* b2   = (const float*)d_in[20];
  const float* g1   = (const float*)d_in[21];
  const float* g2   = (const float*)d_in[22];
  const float* lnos = (const float*)d_in[23];
  const float* lnob = (const float*)d_in[24];

  // --- workspace layout in BYTES (~87 MB; ws_size >= 170 MB established) ---
  char* wsb = (char*)d_ws;
  size_t off = 0;
  float*         h    = (float*)(wsb + off);         off += (size_t)NN * 128 * 4;
  ushort_t*      hn   = (ushort_t*)(wsb + off);      off += (size_t)NN * 128 * 2;
  ushort_t*      qbuf = (ushort_t*)(wsb + off);      off += (size_t)NN * 512 * 2;
  unsigned char* kv8  = (unsigned char*)(wsb + off); off += (size_t)NN * 1024;
  ushort_t*      xrb  = (ushort_t*)(wsb + off);      off += (size_t)NN * 128 * 2;
  ushort_t*      tb   = (ushort_t*)(wsb + off);      off += (size_t)NN * 512 * 2;
  ushort_t*      wt   = (ushort_t*)(wsb + off);      off += (size_t)688128 * 2;
  float*         bcat = (float*)(wsb + off);         off += (size_t)3328 * 4;
  int*           deg   = (int*)(wsb + off);          off += (size_t)(NN + 128) * 4; // deg + dcnt
  int*           rowst = (int*)(wsb + off);          off += (size_t)(NN + 4) * 4;
  int*           cur   = (int*)(wsb + off);          off += (size_t)NN * 4;
  int*           srcs  = (int*)(wsb + off);          off += (size_t)NE * 4;
  int*           dcur  = (int*)(wsb + off);          off += (size_t)128 * 4;
  int*           perm  = (int*)(wsb + off);          off += (size_t)NN * 4;
  int* dcnt = deg + NN;
  ushort_t* Wcat = wt;                 // 2x(1664x128)
  ushort_t* W1t  = wt + 425984;        // 2x(512x128)
  ushort_t* W2t  = wt + 557056;        // 2x(128x512)

  // weights/bias/deg+dcnt-zero first (zero precedes k_hist/k_dhist in stream order)
  k_wt<<<2780, 256, 0, stream>>>(Wq, Wk, Wv, Wsk, W1, W2, bq, bk, bv, bsk, wt, bcat, deg);
  k_hist<<<(NE + 255) / 256, 256, 0, stream>>>(ei, deg);
  k_scan<<<1, 1024, 0, stream>>>(deg, rowst, cur);
  k_scatter<<<(NE + 255) / 256, 256, 0, stream>>>(ei, cur, srcs);
  k_dhist<<<(NN + 255) / 256, 256, 0, stream>>>(deg, dcnt);
  k_dscan<<<1, 64, 0, stream>>>(dcnt, dcur);
  k_dscatter<<<(NN + 255) / 256, 256, 0, stream>>>(deg, dcur, perm);
  k_inproj<<<NN / 16, 128, 0, stream>>>(x, Win, bin, h, ln1s, ln1b, hn);

  for (int l = 0; l < 2; l++){
    if (l == 1)
      k_ln<1><<<(NN + 3) / 4, 256, 0, stream>>>(h, ln1s + 128, ln1b + 128, hn, NN);
    k_mm<3><<<157 * 13, 256, 0, stream>>>(hn, NN, 128, Wcat + (size_t)l * 212992, bcat + l * 1664,
                                          nullptr, 0, nullptr, qbuf, kv8, xrb, 13);
    k_attn<<<(NN + 3) / 4, 256, 0, stream>>>(qbuf, kv8, rowst, srcs, perm, xrb, Wbt + l * 384,
                                             g1 + l, h, ln2s + l * 128, ln2b + l * 128, hn);
    k_mm<1><<<157 * 4, 256, 0, stream>>>(hn, NN, 128, W1t + (size_t)l * 65536, b1 + l * 512,
                                         tb, 512, nullptr, nullptr, nullptr, nullptr, 4);
    k_mm<2><<<157, 256, 0, stream>>>(tb, NN, 512, W2t + (size_t)l * 65536, b2 + l * 128,
                                     h, 128, g2 + l, nullptr, nullptr, nullptr, 1);
  }
  k_ln<0><<<(NN + 3) / 4, 256, 0, stream>>>(h, lnos, lnob, (float*)d_out, NN);
}

// Round 12
// 439.642 us; speedup vs baseline: 1.2773x; 1.2773x over previous
//
#include <hip/hip_runtime.h>
#include <hip/hip_bf16.h>
#include <math.h>

#define NN 20000
#define NE 320000

typedef unsigned short ushort_t;
typedef unsigned short ushortx8 __attribute__((ext_vector_type(8)));
typedef short s16x8 __attribute__((ext_vector_type(8)));
typedef float f32x4 __attribute__((ext_vector_type(4)));
typedef float f32x2 __attribute__((ext_vector_type(2)));

__device__ __forceinline__ float us2f(unsigned short u){
  return __uint_as_float(((unsigned)u) << 16);
}
__device__ __forceinline__ unsigned short f2us(float f){
  unsigned u = __float_as_uint(f);
  unsigned r = (u + 0x7fffu + ((u >> 16) & 1u)) >> 16;   // RNE
  return (unsigned short)r;
}
__device__ __forceinline__ void e4m3x8_to_f32(uint2 d, float* out){
  f32x2 a = __builtin_amdgcn_cvt_pk_f32_fp8(d.x, false);
  f32x2 b = __builtin_amdgcn_cvt_pk_f32_fp8(d.x, true);
  f32x2 c = __builtin_amdgcn_cvt_pk_f32_fp8(d.y, false);
  f32x2 e = __builtin_amdgcn_cvt_pk_f32_fp8(d.y, true);
  out[0] = a.x; out[1] = a.y; out[2] = b.x; out[3] = b.y;
  out[4] = c.x; out[5] = c.y; out[6] = e.x; out[7] = e.y;
}
__device__ __forceinline__ uint2 f32x8_to_e4m3(const float* f){
  unsigned lo = __builtin_amdgcn_cvt_pk_fp8_f32(f[0], f[1], 0u, false);
  lo = __builtin_amdgcn_cvt_pk_fp8_f32(f[2], f[3], lo, true);
  unsigned hi = __builtin_amdgcn_cvt_pk_fp8_f32(f[4], f[5], 0u, false);
  hi = __builtin_amdgcn_cvt_pk_fp8_f32(f[6], f[7], hi, true);
  return make_uint2(lo, hi);
}
// DPP butterfly add within 16-lane rows. Bit-identical to the shfl_xor chain.
template<int CTRL>
__device__ __forceinline__ float dpp_add(float x){
  int t = __builtin_amdgcn_update_dpp(0, __float_as_int(x), CTRL, 0xf, 0xf, true);
  return x + __int_as_float(t);
}
__device__ __forceinline__ float red16(float p){
  p = dpp_add<0xB1>(p);    // quad_perm [1,0,3,2]  == xor 1
  p = dpp_add<0x4E>(p);    // quad_perm [2,3,0,1]  == xor 2
  p = dpp_add<0x141>(p);   // row_half_mirror      == xor 4 (value-equal)
  p = dpp_add<0x140>(p);   // row_mirror           == xor 8 (value-equal)
  return p;
}

// ---------------- CSR build ----------------
__global__ void k_hist(const int* __restrict__ ei, int* __restrict__ deg){
  int e = blockIdx.x * 256 + threadIdx.x;
  if (e < NE) atomicAdd(&deg[ei[NE + e]], 1);
}

__global__ __launch_bounds__(1024) void k_scan(const int* __restrict__ deg,
                                               int* __restrict__ rowst,
                                               int* __restrict__ cur){
  __shared__ int ws[16];
  int tid = threadIdx.x;
  int lane = tid & 63, wid = tid >> 6;
  int base = tid * 20;
  int v[20];
  int s = 0;
  #pragma unroll
  for (int u = 0; u < 20; u++){
    int i = base + u;
    int d = (i < NN) ? deg[i] : 0;
    v[u] = s;
    s += d;
  }
  int incl = s;
  #pragma unroll
  for (int off = 1; off < 64; off <<= 1){
    int t = __shfl_up(incl, off);
    if (lane >= off) incl += t;
  }
  if (lane == 63) ws[wid] = incl;
  __syncthreads();
  int woff = 0;
  #pragma unroll
  for (int k2 = 0; k2 < 16; k2++) if (k2 < wid) woff += ws[k2];
  int toff = woff + incl - s;
  #pragma unroll
  for (int u = 0; u < 20; u++){
    int i = base + u;
    if (i < NN){ int e = toff + v[u]; rowst[i] = e; cur[i] = e; }
  }
  if (tid == 1023) rowst[NN] = toff + s;
}

__global__ void k_scatter(const int* __restrict__ ei, int* __restrict__ cur,
                          int* __restrict__ srcs){
  int e = blockIdx.x * 256 + threadIdx.x;
  if (e < NE){
    int s = ei[e];
    int d = ei[NE + e];
    int p = atomicAdd(&cur[d], 1);
    srcs[p] = s;
  }
}

// ------- weight convert+transpose + bias concat + deg zero (one kernel) -------
__global__ void k_wt(const float* __restrict__ Wq, const float* __restrict__ Wk,
                     const float* __restrict__ Wv, const float* __restrict__ Wsk,
                     const float* __restrict__ W1, const float* __restrict__ W2,
                     const float* __restrict__ bq, const float* __restrict__ bk,
                     const float* __restrict__ bv, const float* __restrict__ bsk,
                     ushort_t* __restrict__ out, float* __restrict__ bcat,
                     int* __restrict__ deg){
  int f = blockIdx.x * 256 + threadIdx.x;
  if (f < 688128){
    float val;
    if (f < 425984){
      int l = f / 212992, idx = f % 212992;
      int n = idx / 128, kk = idx % 128;
      if (n < 512)       val = Wq[(size_t)l * 65536 + kk * 512 + n];
      else if (n < 1024) val = Wk[(size_t)l * 65536 + kk * 512 + (n - 512)];
      else if (n < 1536) val = Wv[(size_t)l * 65536 + kk * 512 + (n - 1024)];
      else               val = Wsk[(size_t)l * 16384 + kk * 128 + (n - 1536)];
    } else if (f < 557056){
      int idx = f - 425984;
      int l = idx / 65536, r = idx % 65536;
      int n = r / 128, kk = r % 128;
      val = W1[(size_t)l * 65536 + kk * 512 + n];
    } else {
      int idx = f - 557056;
      int l = idx / 65536, r = idx % 65536;
      int n = r / 512, kk = r % 512;
      val = W2[(size_t)l * 65536 + kk * 128 + n];
    }
    out[f] = f2us(val);
  } else if (f < 691456){
    int i = f - 688128;
    int l = i / 1664, c = i % 1664;
    float v;
    if (c < 512)       v = bq[l * 512 + c];
    else if (c < 1024) v = bk[l * 512 + c - 512];
    else if (c < 1536) v = bv[l * 512 + c - 1024];
    else               v = bsk[l * 128 + c - 1536];
    bcat[i] = v;
  } else if (f < 711456){
    deg[f - 691456] = 0;
  }
}

// ------- input projection: h = x@Win + b_in (16 rows/block) + fused ln1(l=0) -------
__global__ __launch_bounds__(128) void k_inproj(const float* __restrict__ x,
                                                const float* __restrict__ Win,
                                                const float* __restrict__ bin,
                                                float* __restrict__ h,
                                                const float* __restrict__ sc,
                                                const float* __restrict__ bi,
                                                ushort_t* __restrict__ hn){
  __shared__ float sW[32 * 128];
  __shared__ float sx[16][32];
  int tid = threadIdx.x;
  for (int i = 0; i < 32; i++) sW[i * 128 + tid] = Win[i * 128 + tid];
  int r0 = blockIdx.x * 16;
  for (int rr = tid >> 5; rr < 16; rr += 4){
    int gr = r0 + rr;
    sx[rr][tid & 31] = (gr < NN) ? x[(size_t)gr * 32 + (tid & 31)] : 0.f;
  }
  __syncthreads();
  float bias = bin[tid];
  for (int r = 0; r < 16; r++){
    int gr = r0 + r;
    if (gr >= NN) break;
    float acc = bias;
    #pragma unroll
    for (int k2 = 0; k2 < 32; k2++) acc += sx[r][k2] * sW[k2 * 128 + tid];
    h[(size_t)gr * 128 + tid] = acc;
  }
  __threadfence_block();
  __syncthreads();
  int lane = tid & 63, wv = tid >> 6;
  for (int rr = 0; rr < 8; rr++){
    int r = wv * 8 + rr;
    int gr = r0 + r;
    if (gr >= NN) continue;
    const float* p = h + (size_t)gr * 128 + lane * 2;
    float x0 = p[0], x1 = p[1];
    float sum = x0 + x1;
    for (int m = 1; m < 64; m <<= 1) sum += __shfl_xor(sum, m);
    float mean = sum * (1.f / 128.f);
    float d0 = x0 - mean, d1 = x1 - mean;
    float vs = d0 * d0 + d1 * d1;
    for (int m = 1; m < 64; m <<= 1) vs += __shfl_xor(vs, m);
    float rstd = rsqrtf(vs * (1.f / 128.f) + 1e-5f);
    int d = lane * 2;
    ushort_t* o = hn + (size_t)gr * 128 + d;
    o[0] = f2us(d0 * rstd * sc[d] + bi[d]);
    o[1] = f2us(d1 * rstd * sc[d + 1] + bi[d + 1]);
  }
}

// ---------------- LayerNorm (wave per row); OUTBF16: write bf16 else fp32 ----------------
template<int OUTBF16>
__global__ void k_ln(const float* __restrict__ in, const float* __restrict__ sc,
                     const float* __restrict__ bi, void* __restrict__ outp, int rows){
  int row = blockIdx.x * 4 + (threadIdx.x >> 6);
  int lane = threadIdx.x & 63;
  if (row >= rows) return;
  const float* p = in + (size_t)row * 128 + lane * 2;
  float x0 = p[0], x1 = p[1];
  float sum = x0 + x1;
  for (int m = 1; m < 64; m <<= 1) sum += __shfl_xor(sum, m);
  float mean = sum * (1.f / 128.f);
  float d0 = x0 - mean, d1 = x1 - mean;
  float vs = d0 * d0 + d1 * d1;
  for (int m = 1; m < 64; m <<= 1) vs += __shfl_xor(vs, m);
  float rstd = rsqrtf(vs * (1.f / 128.f) + 1e-5f);
  int d = lane * 2;
  float o0 = d0 * rstd * sc[d] + bi[d];
  float o1 = d1 * rstd * sc[d + 1] + bi[d + 1];
  if (OUTBF16){
    ushort_t* o = (ushort_t*)outp + (size_t)row * 128 + d;
    o[0] = f2us(o0); o[1] = f2us(o1);
  } else {
    float* o = (float*)outp + (size_t)row * 128 + d;
    o[0] = o0; o[1] = o1;
  }
}

// ------- MFMA GEMM: C[M,N] = A[M,K](bf16) @ Bt[N,K](bf16)^T + bias -------
// MODE 1: gelu -> bf16 C (LDS epilogue)   MODE 2: C(f32) += g*(acc+bias) (direct)
// MODE 3: QKVS split -> q bf16 | kv fp8 interleaved (8B k | 8B v per 16B) | xr bf16
template<int MODE>
__global__ __launch_bounds__(256) void k_mm(const ushort_t* __restrict__ A, int M, int K,
                                            const ushort_t* __restrict__ Bt,
                                            const float* __restrict__ bias,
                                            void* __restrict__ Cp, int ldc,
                                            const float* __restrict__ gptr,
                                            ushort_t* __restrict__ qout,
                                            unsigned char* __restrict__ kvout,
                                            ushort_t* __restrict__ xrout,
                                            int nbn){
  __shared__ ushort_t smem[2 * 128 * 72];            // As | Bs, reused as Cs (128x136)
  ushort_t* As = smem;
  ushort_t* Bs = smem + 128 * 72;
  int tid = threadIdx.x;
  // bijective XCD swizzle, n fastest within each XCD chunk
  int nwg = gridDim.x;
  int orig = blockIdx.x;
  int q8 = nwg >> 3, r8 = nwg & 7;
  int xcd = orig & 7, jj = orig >> 3;
  int wgid = (xcd < r8) ? (xcd * (q8 + 1) + jj)
                        : (r8 * (q8 + 1) + (xcd - r8) * q8 + jj);
  int m0 = (wgid / nbn) * 128, n0 = (wgid % nbn) * 128;
  int lane = tid & 63, w = tid >> 6;
  int wm = (w >> 1) * 64, wn = (w & 1) * 64;
  int fr = lane & 15, fq = lane >> 4;
  f32x4 acc[4][4];
  #pragma unroll
  for (int i = 0; i < 4; i++)
    #pragma unroll
    for (int j = 0; j < 4; j++) acc[i][j] = (f32x4){0.f, 0.f, 0.f, 0.f};

  for (int k0 = 0; k0 < K; k0 += 64){
    __syncthreads();
    #pragma unroll
    for (int it = 0; it < 4; it++){
      int idx = it * 256 + tid;
      int row = idx >> 3, ks = (idx & 7) * 8;
      int gr = m0 + row; if (gr >= M) gr = M - 1;
      *(ushortx8*)&As[row * 72 + ks] = *(const ushortx8*)(A + (size_t)gr * K + k0 + ks);
      *(ushortx8*)&Bs[row * 72 + ks] = *(const ushortx8*)(Bt + (size_t)(n0 + row) * K + k0 + ks);
    }
    __syncthreads();
    #pragma unroll
    for (int ks = 0; ks < 64; ks += 32){
      s16x8 a[4], b[4];
      #pragma unroll
      for (int i = 0; i < 4; i++)
        a[i] = *(const s16x8*)&As[(wm + i * 16 + fr) * 72 + ks + fq * 8];
      #pragma unroll
      for (int j = 0; j < 4; j++)
        b[j] = *(const s16x8*)&Bs[(wn + j * 16 + fr) * 72 + ks + fq * 8];
      #pragma unroll
      for (int i = 0; i < 4; i++)
        #pragma unroll
        for (int j = 0; j < 4; j++)
          acc[i][j] = __builtin_amdgcn_mfma_f32_16x16x32_bf16(a[i], b[j], acc[i][j], 0, 0, 0);
    }
  }

  if (MODE == 2){
    float g = *gptr;
    #pragma unroll
    for (int i = 0; i < 4; i++){
      int grb = m0 + wm + i * 16 + fq * 4;
      #pragma unroll
      for (int r = 0; r < 4; r++){
        int gr = grb + r;
        if (gr >= M) continue;
        #pragma unroll
        for (int j = 0; j < 4; j++){
          int gc = n0 + wn + j * 16 + fr;
          float c = acc[i][j][r] + bias[gc];
          ((float*)Cp)[(size_t)gr * ldc + gc] += g * c;
        }
      }
    }
    return;
  }

  // ---- LDS-staged epilogue: frags -> bf16 Cs[row][col] (stride 136) -> vector stores ----
  __syncthreads();
  ushort_t* Cs = smem;
  #pragma unroll
  for (int i = 0; i < 4; i++){
    int rowb = wm + i * 16 + fq * 4;
    #pragma unroll
    for (int j = 0; j < 4; j++){
      int col = wn + j * 16 + fr;
      float bv = bias[n0 + col];
      #pragma unroll
      for (int r = 0; r < 4; r++){
        float c = acc[i][j][r] + bv;
        if (MODE == 1) c = 0.5f * c * (1.f + erff(c * 0.70710678118654752f));
        Cs[(rowb + r) * 136 + col] = f2us(c);
      }
    }
  }
  __syncthreads();
  // region is uniform per block: boundaries (512,1024,1536) are multiples of 128
  #pragma unroll
  for (int it = 0; it < 8; it++){
    int idx = it * 256 + tid;
    int row = idx >> 4, seg = idx & 15;
    int gr = m0 + row;
    if (gr >= M) continue;
    ushortx8 cv = *(const ushortx8*)&Cs[row * 136 + seg * 8];
    int gc = n0 + seg * 8;
    if (MODE == 1){
      *(ushortx8*)((ushort_t*)Cp + (size_t)gr * ldc + gc) = cv;
    } else { // MODE 3
      if (n0 < 512){
        *(ushortx8*)(qout + (size_t)gr * 512 + gc) = cv;
      } else if (n0 < 1536){
        float fv[8];
        #pragma unroll
        for (int t = 0; t < 8; t++) fv[t] = us2f(cv[t]);
        uint2 pk = f32x8_to_e4m3(fv);
        if (n0 < 1024){
          *(uint2*)(kvout + (size_t)gr * 1024 + (size_t)((gc - 512) >> 3) * 16) = pk;
        } else {
          *(uint2*)(kvout + (size_t)gr * 1024 + (size_t)((gc - 1024) >> 3) * 16 + 8) = pk;
        }
      } else {
        *(ushortx8*)(xrout + (size_t)gr * 128 + (gc - 1536)) = cv;
      }
    }
  }
}

// ---- FUSED attention: 8 nodes/block (512 thr), straight-line 12/4/1 tiers, DPP reduce ----
#define EDGE_PROC(KVD) {                                                     \
    float kf[8]; e4m3x8_to_f32(make_uint2((KVD).x, (KVD).y), kf);            \
    float p = 0.f;                                                           \
    _Pragma("unroll")                                                        \
    for (int t = 0; t < 8; t++) p += qf[t] * kf[t];                          \
    p = red16(p);                                                            \
    float wgt = __expf(p * scale);                                           \
    float vf[8]; e4m3x8_to_f32(make_uint2((KVD).z, (KVD).w), vf);            \
    l += wgt;                                                                \
    _Pragma("unroll")                                                        \
    for (int t = 0; t < 8; t++) acc[t] += wgt * vf[t];                       \
  }

__global__ __launch_bounds__(512) void k_attn(
                       const ushort_t* __restrict__ q, const unsigned char* __restrict__ kv8,
                       const int* __restrict__ rowst, const int* __restrict__ srcs,
                       const ushort_t* __restrict__ xr, const float* __restrict__ Wb,
                       const float* __restrict__ g1p, float* __restrict__ h,
                       const float* __restrict__ sc2, const float* __restrict__ bi2,
                       ushort_t* __restrict__ hn){
  int n = blockIdx.x * 8 + (threadIdx.x >> 6);
  int lane = threadIdx.x & 63;
  if (n >= NN) return;
  int s0 = rowst[n], s1 = rowst[n + 1];
  int deg = s1 - s0;
  float qf[8];
  {
    ushortx8 qv = *((const ushortx8*)(q + (size_t)n * 512) + lane);
    #pragma unroll
    for (int t = 0; t < 8; t++) qf[t] = us2f(qv[t]);
  }
  const float scale = 0.08838834764831845f;
  const uint4* kvb = (const uint4*)kv8;   // 64 chunks of 16B per node record
  float l = 0.f;
  float acc[8] = {0.f, 0.f, 0.f, 0.f, 0.f, 0.f, 0.f, 0.f};
  for (int c0 = s0; c0 < s1; c0 += 64){
    int rem = s1 - c0; if (rem > 64) rem = 64;
    int se = (lane < rem) ? srcs[c0 + lane] : 0;
    int j = 0;
    for (; j + 12 <= rem; j += 12){
      uint4 kvd[12];
      #pragma unroll
      for (int u = 0; u < 12; u++){
        int sv = __builtin_amdgcn_readlane(se, j + u);   // SGPR -> scalar base
        kvd[u] = kvb[(size_t)sv * 64 + lane];
      }
      #pragma unroll
      for (int u = 0; u < 12; u++) EDGE_PROC(kvd[u]);
    }
    for (; j + 4 <= rem; j += 4){
      uint4 kvd[4];
      #pragma unroll
      for (int u = 0; u < 4; u++){
        int sv = __builtin_amdgcn_readlane(se, j + u);
        kvd[u] = kvb[(size_t)sv * 64 + lane];
      }
      #pragma unroll
      for (int u = 0; u < 4; u++) EDGE_PROC(kvd[u]);
    }
    for (; j < rem; j++){
      int sv0 = __builtin_amdgcn_readlane(se, j);
      uint4 kvd = kvb[(size_t)sv0 * 64 + lane];
      EDGE_PROC(kvd);
    }
  }
  float inv = deg ? (0.25f / l) : 0.f;   // head-mean folded; deg==0 -> out=0
  #pragma unroll
  for (int t = 0; t < 8; t++){
    float r = acc[t] * inv;
    r += __shfl_xor(r, 16); r += __shfl_xor(r, 32);
    acc[t] = r;
  }
  // ---- epilogue on lanes 0..15: beta gate + residual + ln2 ----
  if (lane < 16){
    int d = lane * 8;
    float xv[8];
    {
      ushortx8 xrv = *(const ushortx8*)(xr + (size_t)n * 128 + d);
      #pragma unroll
      for (int t = 0; t < 8; t++) xv[t] = us2f(xrv[t]);
    }
    float pp = 0.f;
    #pragma unroll
    for (int t = 0; t < 8; t++){
      float w0 = Wb[d + t], w1 = Wb[128 + d + t], w2 = Wb[256 + d + t];
      pp += acc[t] * (w0 + w2) + xv[t] * (w1 - w2);
    }
    pp = red16(pp);
    float beta = 1.f / (1.f + __expf(-pp));
    float g = *g1p;
    float* hp = h + (size_t)n * 128 + d;
    float hv[8];
    {
      float4 h0 = *(const float4*)(hp);
      float4 h1 = *(const float4*)(hp + 4);
      hv[0]=h0.x; hv[1]=h0.y; hv[2]=h0.z; hv[3]=h0.w;
      hv[4]=h1.x; hv[5]=h1.y; hv[6]=h1.z; hv[7]=h1.w;
    }
    #pragma unroll
    for (int t = 0; t < 8; t++)
      hv[t] += g * (beta * xv[t] + (1.f - beta) * acc[t]);
    float s = 0.f;
    #pragma unroll
    for (int t = 0; t < 8; t++) s += hv[t];
    s = red16(s);
    float mean = s * (1.f / 128.f);
    float vs = 0.f;
    #pragma unroll
    for (int t = 0; t < 8; t++){ float dd = hv[t] - mean; vs += dd * dd; }
    vs = red16(vs);
    float rstd = rsqrtf(vs * (1.f / 128.f) + 1e-5f);
    *(float4*)(hp) = make_float4(hv[0], hv[1], hv[2], hv[3]);
    *(float4*)(hp + 4) = make_float4(hv[4], hv[5], hv[6], hv[7]);
    ushortx8 hno;
    #pragma unroll
    for (int t = 0; t < 8; t++)
      hno[t] = f2us((hv[t] - mean) * rstd * sc2[d + t] + bi2[d + t]);
    *(ushortx8*)(hn + (size_t)n * 128 + d) = hno;
  }
}

extern "C" void kernel_launch(void* const* d_in, const int* in_sizes, int n_in,
                              void* d_out, int out_size, void* d_ws, size_t ws_size,
                              hipStream_t stream){
  const float* x    = (const float*)d_in[0];
  const int*   ei   = (const int*)d_in[1];
  const float* Win  = (const float*)d_in[2];
  const float* bin  = (const float*)d_in[3];
  const float* ln1s = (const float*)d_in[4];
  const float* ln1b = (const float*)d_in[5];
  const float* Wq   = (const float*)d_in[6];
  const float* bq   = (const float*)d_in[7];
  const float* Wk   = (const float*)d_in[8];
  const float* bk   = (const float*)d_in[9];
  const float* Wv   = (const float*)d_in[10];
  const float* bv   = (const float*)d_in[11];
  const float* Wsk  = (const float*)d_in[12];
  const float* bsk  = (const float*)d_in[13];
  const float* Wbt  = (const float*)d_in[14];
  const float* ln2s = (const float*)d_in[15];
  const float* ln2b = (const float*)d_in[16];
  const float* W1   = (const float*)d_in[17];
  const float* b1   = (const float*)d_in[18];
  const float* W2   = (const float*)d_in[19];
  const float* b2   = (const float*)d_in[20];
  const float* g1   = (const float*)d_in[21];
  const float* g2   = (const float*)d_in[22];
  const float* lnos = (const float*)d_in[23];
  const float* lnob = (const float*)d_in[24];

  // --- workspace layout in BYTES (~87 MB; ws_size >= 170 MB established) ---
  char* wsb = (char*)d_ws;
  size_t off = 0;
  float*         h    = (float*)(wsb + off);         off += (size_t)NN * 128 * 4;
  ushort_t*      hn   = (ushort_t*)(wsb + off);      off += (size_t)NN * 128 * 2;
  ushort_t*      qbuf = (ushort_t*)(wsb + off);      off += (size_t)NN * 512 * 2;
  unsigned char* kv8  = (unsigned char*)(wsb + off); off += (size_t)NN * 1024;
  ushort_t*      xrb  = (ushort_t*)(wsb + off);      off += (size_t)NN * 128 * 2;
  ushort_t*      tb   = (ushort_t*)(wsb + off);      off += (size_t)NN * 512 * 2;
  ushort_t*      wt   = (ushort_t*)(wsb + off);      off += (size_t)688128 * 2;
  float*         bcat = (float*)(wsb + off);         off += (size_t)3328 * 4;
  int*           deg   = (int*)(wsb + off);          off += (size_t)NN * 4;
  int*           rowst = (int*)(wsb + off);          off += (size_t)(NN + 4) * 4;
  int*           cur   = (int*)(wsb + off);          off += (size_t)NN * 4;
  int*           srcs  = (int*)(wsb + off);          off += (size_t)NE * 4;
  ushort_t* Wcat = wt;                 // 2x(1664x128)
  ushort_t* W1t  = wt + 425984;        // 2x(512x128)
  ushort_t* W2t  = wt + 557056;        // 2x(128x512)

  // weights/bias/deg-zero first (deg zero precedes k_hist in stream order)
  k_wt<<<2780, 256, 0, stream>>>(Wq, Wk, Wv, Wsk, W1, W2, bq, bk, bv, bsk, wt, bcat, deg);
  k_hist<<<(NE + 255) / 256, 256, 0, stream>>>(ei, deg);
  k_scan<<<1, 1024, 0, stream>>>(deg, rowst, cur);
  k_scatter<<<(NE + 255) / 256, 256, 0, stream>>>(ei, cur, srcs);
  k_inproj<<<NN / 16, 128, 0, stream>>>(x, Win, bin, h, ln1s, ln1b, hn);

  for (int l = 0; l < 2; l++){
    if (l == 1)
      k_ln<1><<<(NN + 3) / 4, 256, 0, stream>>>(h, ln1s + 128, ln1b + 128, hn, NN);
    k_mm<3><<<157 * 13, 256, 0, stream>>>(hn, NN, 128, Wcat + (size_t)l * 212992, bcat + l * 1664,
                                          nullptr, 0, nullptr, qbuf, kv8, xrb, 13);
    k_attn<<<(NN + 7) / 8, 512, 0, stream>>>(qbuf, kv8, rowst, srcs, xrb, Wbt + l * 384,
                                             g1 + l, h, ln2s + l * 128, ln2b + l * 128, hn);
    k_mm<1><<<157 * 4, 256, 0, stream>>>(hn, NN, 128, W1t + (size_t)l * 65536, b1 + l * 512,
                                         tb, 512, nullptr, nullptr, nullptr, nullptr, 4);
    k_mm<2><<<157, 256, 0, stream>>>(tb, NN, 512, W2t + (size_t)l * 65536, b2 + l * 128,
                                     h, 128, g2 + l, nullptr, nullptr, nullptr, 1);
  }
  k_ln<0><<<(NN + 3) / 4, 256, 0, stream>>>(h, lnos, lnob, (float*)d_out, NN);
}

// Round 13
// 431.007 us; speedup vs baseline: 1.3028x; 1.0200x over previous
//
#include <hip/hip_runtime.h>
#include <hip/hip_bf16.h>
#include <math.h>

#define NN 20000
#define NE 320000

typedef unsigned short ushort_t;
typedef unsigned short ushortx8 __attribute__((ext_vector_type(8)));
typedef short s16x8 __attribute__((ext_vector_type(8)));
typedef float f32x4 __attribute__((ext_vector_type(4)));
typedef float f32x2 __attribute__((ext_vector_type(2)));

__device__ __forceinline__ float us2f(unsigned short u){
  return __uint_as_float(((unsigned)u) << 16);
}
__device__ __forceinline__ unsigned short f2us(float f){
  unsigned u = __float_as_uint(f);
  unsigned r = (u + 0x7fffu + ((u >> 16) & 1u)) >> 16;   // RNE
  return (unsigned short)r;
}
__device__ __forceinline__ void e4m3x8_to_f32(uint2 d, float* out){
  f32x2 a = __builtin_amdgcn_cvt_pk_f32_fp8(d.x, false);
  f32x2 b = __builtin_amdgcn_cvt_pk_f32_fp8(d.x, true);
  f32x2 c = __builtin_amdgcn_cvt_pk_f32_fp8(d.y, false);
  f32x2 e = __builtin_amdgcn_cvt_pk_f32_fp8(d.y, true);
  out[0] = a.x; out[1] = a.y; out[2] = b.x; out[3] = b.y;
  out[4] = c.x; out[5] = c.y; out[6] = e.x; out[7] = e.y;
}
__device__ __forceinline__ uint2 f32x8_to_e4m3(const float* f){
  unsigned lo = __builtin_amdgcn_cvt_pk_fp8_f32(f[0], f[1], 0u, false);
  lo = __builtin_amdgcn_cvt_pk_fp8_f32(f[2], f[3], lo, true);
  unsigned hi = __builtin_amdgcn_cvt_pk_fp8_f32(f[4], f[5], 0u, false);
  hi = __builtin_amdgcn_cvt_pk_fp8_f32(f[6], f[7], hi, true);
  return make_uint2(lo, hi);
}
// DPP butterfly add within 16-lane rows. Bit-identical to the shfl_xor chain.
template<int CTRL>
__device__ __forceinline__ float dpp_add(float x){
  int t = __builtin_amdgcn_update_dpp(0, __float_as_int(x), CTRL, 0xf, 0xf, true);
  return x + __int_as_float(t);
}
__device__ __forceinline__ float red16(float p){
  p = dpp_add<0xB1>(p);    // quad_perm [1,0,3,2]  == xor 1
  p = dpp_add<0x4E>(p);    // quad_perm [2,3,0,1]  == xor 2
  p = dpp_add<0x141>(p);   // row_half_mirror      == xor 4 (value-equal)
  p = dpp_add<0x140>(p);   // row_mirror           == xor 8 (value-equal)
  return p;
}

// ---------------- CSR build ----------------
__global__ void k_hist(const int* __restrict__ ei, int* __restrict__ deg){
  int e = blockIdx.x * 256 + threadIdx.x;
  if (e < NE) atomicAdd(&deg[ei[NE + e]], 1);
}

__global__ __launch_bounds__(1024) void k_scan(const int* __restrict__ deg,
                                               int* __restrict__ rowst,
                                               int* __restrict__ cur){
  __shared__ int ws[16];
  int tid = threadIdx.x;
  int lane = tid & 63, wid = tid >> 6;
  int base = tid * 20;
  int v[20];
  int s = 0;
  #pragma unroll
  for (int u = 0; u < 20; u++){
    int i = base + u;
    int d = (i < NN) ? deg[i] : 0;
    v[u] = s;
    s += d;
  }
  int incl = s;
  #pragma unroll
  for (int off = 1; off < 64; off <<= 1){
    int t = __shfl_up(incl, off);
    if (lane >= off) incl += t;
  }
  if (lane == 63) ws[wid] = incl;
  __syncthreads();
  int woff = 0;
  #pragma unroll
  for (int k2 = 0; k2 < 16; k2++) if (k2 < wid) woff += ws[k2];
  int toff = woff + incl - s;
  #pragma unroll
  for (int u = 0; u < 20; u++){
    int i = base + u;
    if (i < NN){ int e = toff + v[u]; rowst[i] = e; cur[i] = e; }
  }
  if (tid == 1023) rowst[NN] = toff + s;
}

__global__ void k_scatter(const int* __restrict__ ei, int* __restrict__ cur,
                          int* __restrict__ srcs){
  int e = blockIdx.x * 256 + threadIdx.x;
  if (e < NE){
    int s = ei[e];
    int d = ei[NE + e];
    int p = atomicAdd(&cur[d], 1);
    srcs[p] = s;
  }
}

// ------- weight convert+transpose + bias concat + deg zero (one kernel) -------
__global__ void k_wt(const float* __restrict__ Wq, const float* __restrict__ Wk,
                     const float* __restrict__ Wv, const float* __restrict__ Wsk,
                     const float* __restrict__ W1, const float* __restrict__ W2,
                     const float* __restrict__ bq, const float* __restrict__ bk,
                     const float* __restrict__ bv, const float* __restrict__ bsk,
                     ushort_t* __restrict__ out, float* __restrict__ bcat,
                     int* __restrict__ deg){
  int f = blockIdx.x * 256 + threadIdx.x;
  if (f < 688128){
    float val;
    if (f < 425984){
      int l = f / 212992, idx = f % 212992;
      int n = idx / 128, kk = idx % 128;
      if (n < 512)       val = Wq[(size_t)l * 65536 + kk * 512 + n];
      else if (n < 1024) val = Wk[(size_t)l * 65536 + kk * 512 + (n - 512)];
      else if (n < 1536) val = Wv[(size_t)l * 65536 + kk * 512 + (n - 1024)];
      else               val = Wsk[(size_t)l * 16384 + kk * 128 + (n - 1536)];
    } else if (f < 557056){
      int idx = f - 425984;
      int l = idx / 65536, r = idx % 65536;
      int n = r / 128, kk = r % 128;
      val = W1[(size_t)l * 65536 + kk * 512 + n];
    } else {
      int idx = f - 557056;
      int l = idx / 65536, r = idx % 65536;
      int n = r / 512, kk = r % 512;
      val = W2[(size_t)l * 65536 + kk * 128 + n];
    }
    out[f] = f2us(val);
  } else if (f < 691456){
    int i = f - 688128;
    int l = i / 1664, c = i % 1664;
    float v;
    if (c < 512)       v = bq[l * 512 + c];
    else if (c < 1024) v = bk[l * 512 + c - 512];
    else if (c < 1536) v = bv[l * 512 + c - 1024];
    else               v = bsk[l * 128 + c - 1536];
    bcat[i] = v;
  } else if (f < 711456){
    deg[f - 691456] = 0;
  }
}

// ------- input projection: h = x@Win + b_in (16 rows/block) + fused ln1(l=0) -------
__global__ __launch_bounds__(128) void k_inproj(const float* __restrict__ x,
                                                const float* __restrict__ Win,
                                                const float* __restrict__ bin,
                                                float* __restrict__ h,
                                                const float* __restrict__ sc,
                                                const float* __restrict__ bi,
                                                ushort_t* __restrict__ hn){
  __shared__ float sW[32 * 128];
  __shared__ float sx[16][32];
  int tid = threadIdx.x;
  for (int i = 0; i < 32; i++) sW[i * 128 + tid] = Win[i * 128 + tid];
  int r0 = blockIdx.x * 16;
  for (int rr = tid >> 5; rr < 16; rr += 4){
    int gr = r0 + rr;
    sx[rr][tid & 31] = (gr < NN) ? x[(size_t)gr * 32 + (tid & 31)] : 0.f;
  }
  __syncthreads();
  float bias = bin[tid];
  for (int r = 0; r < 16; r++){
    int gr = r0 + r;
    if (gr >= NN) break;
    float acc = bias;
    #pragma unroll
    for (int k2 = 0; k2 < 32; k2++) acc += sx[r][k2] * sW[k2 * 128 + tid];
    h[(size_t)gr * 128 + tid] = acc;
  }
  __threadfence_block();
  __syncthreads();
  int lane = tid & 63, wv = tid >> 6;
  for (int rr = 0; rr < 8; rr++){
    int r = wv * 8 + rr;
    int gr = r0 + r;
    if (gr >= NN) continue;
    const float* p = h + (size_t)gr * 128 + lane * 2;
    float x0 = p[0], x1 = p[1];
    float sum = x0 + x1;
    for (int m = 1; m < 64; m <<= 1) sum += __shfl_xor(sum, m);
    float mean = sum * (1.f / 128.f);
    float d0 = x0 - mean, d1 = x1 - mean;
    float vs = d0 * d0 + d1 * d1;
    for (int m = 1; m < 64; m <<= 1) vs += __shfl_xor(vs, m);
    float rstd = rsqrtf(vs * (1.f / 128.f) + 1e-5f);
    int d = lane * 2;
    ushort_t* o = hn + (size_t)gr * 128 + d;
    o[0] = f2us(d0 * rstd * sc[d] + bi[d]);
    o[1] = f2us(d1 * rstd * sc[d + 1] + bi[d + 1]);
  }
}

// ---------------- LayerNorm (wave per row); OUTBF16: write bf16 else fp32 ----------------
template<int OUTBF16>
__global__ void k_ln(const float* __restrict__ in, const float* __restrict__ sc,
                     const float* __restrict__ bi, void* __restrict__ outp, int rows){
  int row = blockIdx.x * 4 + (threadIdx.x >> 6);
  int lane = threadIdx.x & 63;
  if (row >= rows) return;
  const float* p = in + (size_t)row * 128 + lane * 2;
  float x0 = p[0], x1 = p[1];
  float sum = x0 + x1;
  for (int m = 1; m < 64; m <<= 1) sum += __shfl_xor(sum, m);
  float mean = sum * (1.f / 128.f);
  float d0 = x0 - mean, d1 = x1 - mean;
  float vs = d0 * d0 + d1 * d1;
  for (int m = 1; m < 64; m <<= 1) vs += __shfl_xor(vs, m);
  float rstd = rsqrtf(vs * (1.f / 128.f) + 1e-5f);
  int d = lane * 2;
  float o0 = d0 * rstd * sc[d] + bi[d];
  float o1 = d1 * rstd * sc[d + 1] + bi[d + 1];
  if (OUTBF16){
    ushort_t* o = (ushort_t*)outp + (size_t)row * 128 + d;
    o[0] = f2us(o0); o[1] = f2us(o1);
  } else {
    float* o = (float*)outp + (size_t)row * 128 + d;
    o[0] = o0; o[1] = o1;
  }
}

// ------- MFMA GEMM: C[M,N] = A[M,K](bf16) @ Bt[N,K](bf16)^T + bias -------
// MODE 1: gelu -> bf16 C (LDS epilogue)   MODE 2: C(f32) += g*(acc+bias) (direct)
// MODE 3: QKVS split -> q bf16 | kv fp8 interleaved (8B k | 8B v per 16B) | xr bf16
template<int MODE>
__global__ __launch_bounds__(256) void k_mm(const ushort_t* __restrict__ A, int M, int K,
                                            const ushort_t* __restrict__ Bt,
                                            const float* __restrict__ bias,
                                            void* __restrict__ Cp, int ldc,
                                            const float* __restrict__ gptr,
                                            ushort_t* __restrict__ qout,
                                            unsigned char* __restrict__ kvout,
                                            ushort_t* __restrict__ xrout,
                                            int nbn){
  __shared__ ushort_t smem[2 * 128 * 72];            // As | Bs, reused as Cs (128x136)
  ushort_t* As = smem;
  ushort_t* Bs = smem + 128 * 72;
  int tid = threadIdx.x;
  // bijective XCD swizzle, n fastest within each XCD chunk
  int nwg = gridDim.x;
  int orig = blockIdx.x;
  int q8 = nwg >> 3, r8 = nwg & 7;
  int xcd = orig & 7, jj = orig >> 3;
  int wgid = (xcd < r8) ? (xcd * (q8 + 1) + jj)
                        : (r8 * (q8 + 1) + (xcd - r8) * q8 + jj);
  int m0 = (wgid / nbn) * 128, n0 = (wgid % nbn) * 128;
  int lane = tid & 63, w = tid >> 6;
  int wm = (w >> 1) * 64, wn = (w & 1) * 64;
  int fr = lane & 15, fq = lane >> 4;
  f32x4 acc[4][4];
  #pragma unroll
  for (int i = 0; i < 4; i++)
    #pragma unroll
    for (int j = 0; j < 4; j++) acc[i][j] = (f32x4){0.f, 0.f, 0.f, 0.f};

  for (int k0 = 0; k0 < K; k0 += 64){
    __syncthreads();
    #pragma unroll
    for (int it = 0; it < 4; it++){
      int idx = it * 256 + tid;
      int row = idx >> 3, ks = (idx & 7) * 8;
      int gr = m0 + row; if (gr >= M) gr = M - 1;
      *(ushortx8*)&As[row * 72 + ks] = *(const ushortx8*)(A + (size_t)gr * K + k0 + ks);
      *(ushortx8*)&Bs[row * 72 + ks] = *(const ushortx8*)(Bt + (size_t)(n0 + row) * K + k0 + ks);
    }
    __syncthreads();
    #pragma unroll
    for (int ks = 0; ks < 64; ks += 32){
      s16x8 a[4], b[4];
      #pragma unroll
      for (int i = 0; i < 4; i++)
        a[i] = *(const s16x8*)&As[(wm + i * 16 + fr) * 72 + ks + fq * 8];
      #pragma unroll
      for (int j = 0; j < 4; j++)
        b[j] = *(const s16x8*)&Bs[(wn + j * 16 + fr) * 72 + ks + fq * 8];
      #pragma unroll
      for (int i = 0; i < 4; i++)
        #pragma unroll
        for (int j = 0; j < 4; j++)
          acc[i][j] = __builtin_amdgcn_mfma_f32_16x16x32_bf16(a[i], b[j], acc[i][j], 0, 0, 0);
    }
  }

  if (MODE == 2){
    float g = *gptr;
    #pragma unroll
    for (int i = 0; i < 4; i++){
      int grb = m0 + wm + i * 16 + fq * 4;
      #pragma unroll
      for (int r = 0; r < 4; r++){
        int gr = grb + r;
        if (gr >= M) continue;
        #pragma unroll
        for (int j = 0; j < 4; j++){
          int gc = n0 + wn + j * 16 + fr;
          float c = acc[i][j][r] + bias[gc];
          ((float*)Cp)[(size_t)gr * ldc + gc] += g * c;
        }
      }
    }
    return;
  }

  // ---- LDS-staged epilogue: frags -> bf16 Cs[row][col] (stride 136) -> vector stores ----
  __syncthreads();
  ushort_t* Cs = smem;
  #pragma unroll
  for (int i = 0; i < 4; i++){
    int rowb = wm + i * 16 + fq * 4;
    #pragma unroll
    for (int j = 0; j < 4; j++){
      int col = wn + j * 16 + fr;
      float bv = bias[n0 + col];
      #pragma unroll
      for (int r = 0; r < 4; r++){
        float c = acc[i][j][r] + bv;
        if (MODE == 1) c = 0.5f * c * (1.f + erff(c * 0.70710678118654752f));
        Cs[(rowb + r) * 136 + col] = f2us(c);
      }
    }
  }
  __syncthreads();
  // region is uniform per block: boundaries (512,1024,1536) are multiples of 128
  #pragma unroll
  for (int it = 0; it < 8; it++){
    int idx = it * 256 + tid;
    int row = idx >> 4, seg = idx & 15;
    int gr = m0 + row;
    if (gr >= M) continue;
    ushortx8 cv = *(const ushortx8*)&Cs[row * 136 + seg * 8];
    int gc = n0 + seg * 8;
    if (MODE == 1){
      *(ushortx8*)((ushort_t*)Cp + (size_t)gr * ldc + gc) = cv;
    } else { // MODE 3
      if (n0 < 512){
        *(ushortx8*)(qout + (size_t)gr * 512 + gc) = cv;
      } else if (n0 < 1536){
        float fv[8];
        #pragma unroll
        for (int t = 0; t < 8; t++) fv[t] = us2f(cv[t]);
        uint2 pk = f32x8_to_e4m3(fv);
        if (n0 < 1024){
          *(uint2*)(kvout + (size_t)gr * 1024 + (size_t)((gc - 512) >> 3) * 16) = pk;
        } else {
          *(uint2*)(kvout + (size_t)gr * 1024 + (size_t)((gc - 1024) >> 3) * 16 + 8) = pk;
        }
      } else {
        *(ushortx8*)(xrout + (size_t)gr * 128 + (gc - 1536)) = cv;
      }
    }
  }
}

// ---- FUSED attention: 4 nodes/block (256 thr), 12/4/1 tiers, DPP reduce ----
// Packed-pair math: dot and accumulate via f32x2 (v_pk_fma_f32); scale*log2e
// pre-folded into q; w = exp2(p) via v_exp_f32. Reassociates the 8-term dot
// (pairwise) -- not bit-identical, but drift ~1ulp in logits vs the dominant
// bf16/fp8 quantization error.
#define EDGE_PROC(KVD) {                                                     \
    f32x2 k01 = __builtin_amdgcn_cvt_pk_f32_fp8((KVD).x, false);             \
    f32x2 k23 = __builtin_amdgcn_cvt_pk_f32_fp8((KVD).x, true);              \
    f32x2 k45 = __builtin_amdgcn_cvt_pk_f32_fp8((KVD).y, false);             \
    f32x2 k67 = __builtin_amdgcn_cvt_pk_f32_fp8((KVD).y, true);              \
    f32x2 p2 = q01 * k01;                                                    \
    p2 = __builtin_elementwise_fma(q23, k23, p2);                            \
    p2 = __builtin_elementwise_fma(q45, k45, p2);                            \
    p2 = __builtin_elementwise_fma(q67, k67, p2);                            \
    float p = red16(p2.x + p2.y);                                            \
    float wgt = __builtin_amdgcn_exp2f(p);                                   \
    f32x2 v01 = __builtin_amdgcn_cvt_pk_f32_fp8((KVD).z, false);             \
    f32x2 v23 = __builtin_amdgcn_cvt_pk_f32_fp8((KVD).z, true);              \
    f32x2 v45 = __builtin_amdgcn_cvt_pk_f32_fp8((KVD).w, false);             \
    f32x2 v67 = __builtin_amdgcn_cvt_pk_f32_fp8((KVD).w, true);              \
    l += wgt;                                                                \
    f32x2 w2 = (f32x2){wgt, wgt};                                            \
    acc2[0] = __builtin_elementwise_fma(w2, v01, acc2[0]);                   \
    acc2[1] = __builtin_elementwise_fma(w2, v23, acc2[1]);                   \
    acc2[2] = __builtin_elementwise_fma(w2, v45, acc2[2]);                   \
    acc2[3] = __builtin_elementwise_fma(w2, v67, acc2[3]);                   \
  }

__global__ __launch_bounds__(256) void k_attn(
                       const ushort_t* __restrict__ q, const unsigned char* __restrict__ kv8,
                       const int* __restrict__ rowst, const int* __restrict__ srcs,
                       const ushort_t* __restrict__ xr, const float* __restrict__ Wb,
                       const float* __restrict__ g1p, float* __restrict__ h,
                       const float* __restrict__ sc2, const float* __restrict__ bi2,
                       ushort_t* __restrict__ hn){
  int n = blockIdx.x * 4 + (threadIdx.x >> 6);
  int lane = threadIdx.x & 63;
  if (n >= NN) return;
  int s0 = rowst[n], s1 = rowst[n + 1];
  int deg = s1 - s0;
  // q pre-scaled by scale*log2(e): exp(p*scale) == exp2(sum (q*qs)·k)
  const float qs = 0.08838834764831845f * 1.4426950408889634f;
  f32x2 q01, q23, q45, q67;
  {
    ushortx8 qv = *((const ushortx8*)(q + (size_t)n * 512) + lane);
    q01 = (f32x2){us2f(qv[0]) * qs, us2f(qv[1]) * qs};
    q23 = (f32x2){us2f(qv[2]) * qs, us2f(qv[3]) * qs};
    q45 = (f32x2){us2f(qv[4]) * qs, us2f(qv[5]) * qs};
    q67 = (f32x2){us2f(qv[6]) * qs, us2f(qv[7]) * qs};
  }
  const uint4* kvb = (const uint4*)kv8;   // 64 chunks of 16B per node record
  float l = 0.f;
  f32x2 acc2[4];
  #pragma unroll
  for (int t = 0; t < 4; t++) acc2[t] = (f32x2){0.f, 0.f};
  for (int c0 = s0; c0 < s1; c0 += 64){
    int rem = s1 - c0; if (rem > 64) rem = 64;
    int se = (lane < rem) ? srcs[c0 + lane] : 0;
    int j = 0;
    for (; j + 12 <= rem; j += 12){
      uint4 kvd[12];
      #pragma unroll
      for (int u = 0; u < 12; u++){
        int sv = __builtin_amdgcn_readlane(se, j + u);   // SGPR -> scalar base
        kvd[u] = kvb[(size_t)sv * 64 + lane];
      }
      #pragma unroll
      for (int u = 0; u < 12; u++) EDGE_PROC(kvd[u]);
    }
    for (; j + 4 <= rem; j += 4){
      uint4 kvd[4];
      #pragma unroll
      for (int u = 0; u < 4; u++){
        int sv = __builtin_amdgcn_readlane(se, j + u);
        kvd[u] = kvb[(size_t)sv * 64 + lane];
      }
      #pragma unroll
      for (int u = 0; u < 4; u++) EDGE_PROC(kvd[u]);
    }
    for (; j < rem; j++){
      int sv0 = __builtin_amdgcn_readlane(se, j);
      uint4 kvd = kvb[(size_t)sv0 * 64 + lane];
      EDGE_PROC(kvd);
    }
  }
  float inv = deg ? (0.25f / l) : 0.f;   // head-mean folded; deg==0 -> out=0
  float accs[8];
  accs[0] = acc2[0].x; accs[1] = acc2[0].y;
  accs[2] = acc2[1].x; accs[3] = acc2[1].y;
  accs[4] = acc2[2].x; accs[5] = acc2[2].y;
  accs[6] = acc2[3].x; accs[7] = acc2[3].y;
  #pragma unroll
  for (int t = 0; t < 8; t++){
    float r = accs[t] * inv;
    r += __shfl_xor(r, 16); r += __shfl_xor(r, 32);
    accs[t] = r;
  }
  // ---- epilogue on lanes 0..15: beta gate + residual + ln2 ----
  if (lane < 16){
    int d = lane * 8;
    float xv[8];
    {
      ushortx8 xrv = *(const ushortx8*)(xr + (size_t)n * 128 + d);
      #pragma unroll
      for (int t = 0; t < 8; t++) xv[t] = us2f(xrv[t]);
    }
    float pp = 0.f;
    #pragma unroll
    for (int t = 0; t < 8; t++){
      float w0 = Wb[d + t], w1 = Wb[128 + d + t], w2 = Wb[256 + d + t];
      pp += accs[t] * (w0 + w2) + xv[t] * (w1 - w2);
    }
    pp = red16(pp);
    float beta = 1.f / (1.f + __expf(-pp));
    float g = *g1p;
    float* hp = h + (size_t)n * 128 + d;
    float hv[8];
    {
      float4 h0 = *(const float4*)(hp);
      float4 h1 = *(const float4*)(hp + 4);
      hv[0]=h0.x; hv[1]=h0.y; hv[2]=h0.z; hv[3]=h0.w;
      hv[4]=h1.x; hv[5]=h1.y; hv[6]=h1.z; hv[7]=h1.w;
    }
    #pragma unroll
    for (int t = 0; t < 8; t++)
      hv[t] += g * (beta * xv[t] + (1.f - beta) * accs[t]);
    float s = 0.f;
    #pragma unroll
    for (int t = 0; t < 8; t++) s += hv[t];
    s = red16(s);
    float mean = s * (1.f / 128.f);
    float vs = 0.f;
    #pragma unroll
    for (int t = 0; t < 8; t++){ float dd = hv[t] - mean; vs += dd * dd; }
    vs = red16(vs);
    float rstd = rsqrtf(vs * (1.f / 128.f) + 1e-5f);
    *(float4*)(hp) = make_float4(hv[0], hv[1], hv[2], hv[3]);
    *(float4*)(hp + 4) = make_float4(hv[4], hv[5], hv[6], hv[7]);
    ushortx8 hno;
    #pragma unroll
    for (int t = 0; t < 8; t++)
      hno[t] = f2us((hv[t] - mean) * rstd * sc2[d + t] + bi2[d + t]);
    *(ushortx8*)(hn + (size_t)n * 128 + d) = hno;
  }
}

extern "C" void kernel_launch(void* const* d_in, const int* in_sizes, int n_in,
                              void* d_out, int out_size, void* d_ws, size_t ws_size,
                              hipStream_t stream){
  const float* x    = (const float*)d_in[0];
  const int*   ei   = (const int*)d_in[1];
  const float* Win  = (const float*)d_in[2];
  const float* bin  = (const float*)d_in[3];
  const float* ln1s = (const float*)d_in[4];
  const float* ln1b = (const float*)d_in[5];
  const float* Wq   = (const float*)d_in[6];
  const float* bq   = (const float*)d_in[7];
  const float* Wk   = (const float*)d_in[8];
  const float* bk   = (const float*)d_in[9];
  const float* Wv   = (const float*)d_in[10];
  const float* bv   = (const float*)d_in[11];
  const float* Wsk  = (const float*)d_in[12];
  const float* bsk  = (const float*)d_in[13];
  const float* Wbt  = (const float*)d_in[14];
  const float* ln2s = (const float*)d_in[15];
  const float* ln2b = (const float*)d_in[16];
  const float* W1   = (const float*)d_in[17];
  const float* b1   = (const float*)d_in[18];
  const float* W2   = (const float*)d_in[19];
  const float* b2   = (const float*)d_in[20];
  const float* g1   = (const float*)d_in[21];
  const float* g2   = (const float*)d_in[22];
  const float* lnos = (const float*)d_in[23];
  const float* lnob = (const float*)d_in[24];

  // --- workspace layout in BYTES (~87 MB; ws_size >= 170 MB established) ---
  char* wsb = (char*)d_ws;
  size_t off = 0;
  float*         h    = (float*)(wsb + off);         off += (size_t)NN * 128 * 4;
  ushort_t*      hn   = (ushort_t*)(wsb + off);      off += (size_t)NN * 128 * 2;
  ushort_t*      qbuf = (ushort_t*)(wsb + off);      off += (size_t)NN * 512 * 2;
  unsigned char* kv8  = (unsigned char*)(wsb + off); off += (size_t)NN * 1024;
  ushort_t*      xrb  = (ushort_t*)(wsb + off);      off += (size_t)NN * 128 * 2;
  ushort_t*      tb   = (ushort_t*)(wsb + off);      off += (size_t)NN * 512 * 2;
  ushort_t*      wt   = (ushort_t*)(wsb + off);      off += (size_t)688128 * 2;
  float*         bcat = (float*)(wsb + off);         off += (size_t)3328 * 4;
  int*           deg   = (int*)(wsb + off);          off += (size_t)NN * 4;
  int*           rowst = (int*)(wsb + off);          off += (size_t)(NN + 4) * 4;
  int*           cur   = (int*)(wsb + off);          off += (size_t)NN * 4;
  int*           srcs  = (int*)(wsb + off);          off += (size_t)NE * 4;
  ushort_t* Wcat = wt;                 // 2x(1664x128)
  ushort_t* W1t  = wt + 425984;        // 2x(512x128)
  ushort_t* W2t  = wt + 557056;        // 2x(128x512)

  // weights/bias/deg-zero first (deg zero precedes k_hist in stream order)
  k_wt<<<2780, 256, 0, stream>>>(Wq, Wk, Wv, Wsk, W1, W2, bq, bk, bv, bsk, wt, bcat, deg);
  k_hist<<<(NE + 255) / 256, 256, 0, stream>>>(ei, deg);
  k_scan<<<1, 1024, 0, stream>>>(deg, rowst, cur);
  k_scatter<<<(NE + 255) / 256, 256, 0, stream>>>(ei, cur, srcs);
  k_inproj<<<NN / 16, 128, 0, stream>>>(x, Win, bin, h, ln1s, ln1b, hn);

  for (int l = 0; l < 2; l++){
    if (l == 1)
      k_ln<1><<<(NN + 3) / 4, 256, 0, stream>>>(h, ln1s + 128, ln1b + 128, hn, NN);
    k_mm<3><<<157 * 13, 256, 0, stream>>>(hn, NN, 128, Wcat + (size_t)l * 212992, bcat + l * 1664,
                                          nullptr, 0, nullptr, qbuf, kv8, xrb, 13);
    k_attn<<<(NN + 3) / 4, 256, 0, stream>>>(qbuf, kv8, rowst, srcs, xrb, Wbt + l * 384,
                                             g1 + l, h, ln2s + l * 128, ln2b + l * 128, hn);
    k_mm<1><<<157 * 4, 256, 0, stream>>>(hn, NN, 128, W1t + (size_t)l * 65536, b1 + l * 512,
                                         tb, 512, nullptr, nullptr, nullptr, nullptr, 4);
    k_mm<2><<<157, 256, 0, stream>>>(tb, NN, 512, W2t + (size_t)l * 65536, b2 + l * 128,
                                     h, 128, g2 + l, nullptr, nullptr, nullptr, 1);
  }
  k_ln<0><<<(NN + 3) / 4, 256, 0, stream>>>(h, lnos, lnob, (float*)d_out, NN);
}

// Round 14
// 412.998 us; speedup vs baseline: 1.3597x; 1.0436x over previous
//
#include <hip/hip_runtime.h>
#include <hip/hip_bf16.h>
#include <math.h>

#define NN 20000
#define NE 320000

typedef unsigned short ushort_t;
typedef unsigned short ushortx8 __attribute__((ext_vector_type(8)));
typedef short s16x8 __attribute__((ext_vector_type(8)));
typedef float f32x4 __attribute__((ext_vector_type(4)));
typedef float f32x2 __attribute__((ext_vector_type(2)));

__device__ __forceinline__ float us2f(unsigned short u){
  return __uint_as_float(((unsigned)u) << 16);
}
__device__ __forceinline__ unsigned short f2us(float f){
  unsigned u = __float_as_uint(f);
  unsigned r = (u + 0x7fffu + ((u >> 16) & 1u)) >> 16;   // RNE
  return (unsigned short)r;
}
__device__ __forceinline__ void e4m3x8_to_f32(uint2 d, float* out){
  f32x2 a = __builtin_amdgcn_cvt_pk_f32_fp8(d.x, false);
  f32x2 b = __builtin_amdgcn_cvt_pk_f32_fp8(d.x, true);
  f32x2 c = __builtin_amdgcn_cvt_pk_f32_fp8(d.y, false);
  f32x2 e = __builtin_amdgcn_cvt_pk_f32_fp8(d.y, true);
  out[0] = a.x; out[1] = a.y; out[2] = b.x; out[3] = b.y;
  out[4] = c.x; out[5] = c.y; out[6] = e.x; out[7] = e.y;
}
__device__ __forceinline__ uint2 f32x8_to_e4m3(const float* f){
  unsigned lo = __builtin_amdgcn_cvt_pk_fp8_f32(f[0], f[1], 0u, false);
  lo = __builtin_amdgcn_cvt_pk_fp8_f32(f[2], f[3], lo, true);
  unsigned hi = __builtin_amdgcn_cvt_pk_fp8_f32(f[4], f[5], 0u, false);
  hi = __builtin_amdgcn_cvt_pk_fp8_f32(f[6], f[7], hi, true);
  return make_uint2(lo, hi);
}
// DPP butterfly add within 16-lane rows. Bit-identical to the shfl_xor chain.
template<int CTRL>
__device__ __forceinline__ float dpp_add(float x){
  int t = __builtin_amdgcn_update_dpp(0, __float_as_int(x), CTRL, 0xf, 0xf, true);
  return x + __int_as_float(t);
}
__device__ __forceinline__ float red16(float p){
  p = dpp_add<0xB1>(p);    // quad_perm [1,0,3,2]  == xor 1
  p = dpp_add<0x4E>(p);    // quad_perm [2,3,0,1]  == xor 2
  p = dpp_add<0x141>(p);   // row_half_mirror      == xor 4 (value-equal)
  p = dpp_add<0x140>(p);   // row_mirror           == xor 8 (value-equal)
  return p;
}

// ---------------- CSR build ----------------
// single atomic pass: rank[e] = arrival order of edge e at its dst bucket
__global__ void k_hist(const int* __restrict__ ei, int* __restrict__ deg,
                       int* __restrict__ rank){
  int e = blockIdx.x * 256 + threadIdx.x;
  if (e < NE) rank[e] = atomicAdd(&deg[ei[NE + e]], 1);
}

__global__ __launch_bounds__(1024) void k_scan(const int* __restrict__ deg,
                                               int* __restrict__ rowst){
  __shared__ int ws[16];
  int tid = threadIdx.x;
  int lane = tid & 63, wid = tid >> 6;
  int base = tid * 20;
  int v[20];
  int s = 0;
  #pragma unroll
  for (int u = 0; u < 20; u++){
    int i = base + u;
    int d = (i < NN) ? deg[i] : 0;
    v[u] = s;
    s += d;
  }
  int incl = s;
  #pragma unroll
  for (int off = 1; off < 64; off <<= 1){
    int t = __shfl_up(incl, off);
    if (lane >= off) incl += t;
  }
  if (lane == 63) ws[wid] = incl;
  __syncthreads();
  int woff = 0;
  #pragma unroll
  for (int k2 = 0; k2 < 16; k2++) if (k2 < wid) woff += ws[k2];
  int toff = woff + incl - s;
  #pragma unroll
  for (int u = 0; u < 20; u++){
    int i = base + u;
    if (i < NN) rowst[i] = toff + v[u];
  }
  if (tid == 1023) rowst[NN] = toff + s;
}

// atomic-free scatter: slot = rowst[dst] + rank
__global__ void k_scatter(const int* __restrict__ ei, const int* __restrict__ rowst,
                          const int* __restrict__ rank, int* __restrict__ srcs){
  int e = blockIdx.x * 256 + threadIdx.x;
  if (e < NE){
    int d = ei[NE + e];
    srcs[rowst[d] + rank[e]] = ei[e];
  }
}

// ------- weight convert+transpose + bias concat + deg zero (one kernel) -------
__global__ void k_wt(const float* __restrict__ Wq, const float* __restrict__ Wk,
                     const float* __restrict__ Wv, const float* __restrict__ Wsk,
                     const float* __restrict__ W1, const float* __restrict__ W2,
                     const float* __restrict__ bq, const float* __restrict__ bk,
                     const float* __restrict__ bv, const float* __restrict__ bsk,
                     ushort_t* __restrict__ out, float* __restrict__ bcat,
                     int* __restrict__ deg){
  int f = blockIdx.x * 256 + threadIdx.x;
  if (f < 688128){
    float val;
    if (f < 425984){
      int l = f / 212992, idx = f % 212992;
      int n = idx / 128, kk = idx % 128;
      if (n < 512)       val = Wq[(size_t)l * 65536 + kk * 512 + n];
      else if (n < 1024) val = Wk[(size_t)l * 65536 + kk * 512 + (n - 512)];
      else if (n < 1536) val = Wv[(size_t)l * 65536 + kk * 512 + (n - 1024)];
      else               val = Wsk[(size_t)l * 16384 + kk * 128 + (n - 1536)];
    } else if (f < 557056){
      int idx = f - 425984;
      int l = idx / 65536, r = idx % 65536;
      int n = r / 128, kk = r % 128;
      val = W1[(size_t)l * 65536 + kk * 512 + n];
    } else {
      int idx = f - 557056;
      int l = idx / 65536, r = idx % 65536;
      int n = r / 512, kk = r % 512;
      val = W2[(size_t)l * 65536 + kk * 128 + n];
    }
    out[f] = f2us(val);
  } else if (f < 691456){
    int i = f - 688128;
    int l = i / 1664, c = i % 1664;
    float v;
    if (c < 512)       v = bq[l * 512 + c];
    else if (c < 1024) v = bk[l * 512 + c - 512];
    else if (c < 1536) v = bv[l * 512 + c - 1024];
    else               v = bsk[l * 128 + c - 1536];
    bcat[i] = v;
  } else if (f < 711456){
    deg[f - 691456] = 0;
  }
}

// ------- input projection: h = x@Win + b_in (16 rows/block) + fused ln1(l=0) -------
__global__ __launch_bounds__(128) void k_inproj(const float* __restrict__ x,
                                                const float* __restrict__ Win,
                                                const float* __restrict__ bin,
                                                float* __restrict__ h,
                                                const float* __restrict__ sc,
                                                const float* __restrict__ bi,
                                                ushort_t* __restrict__ hn){
  __shared__ float sW[32 * 128];
  __shared__ float sx[16][32];
  int tid = threadIdx.x;
  for (int i = 0; i < 32; i++) sW[i * 128 + tid] = Win[i * 128 + tid];
  int r0 = blockIdx.x * 16;
  for (int rr = tid >> 5; rr < 16; rr += 4){
    int gr = r0 + rr;
    sx[rr][tid & 31] = (gr < NN) ? x[(size_t)gr * 32 + (tid & 31)] : 0.f;
  }
  __syncthreads();
  float bias = bin[tid];
  for (int r = 0; r < 16; r++){
    int gr = r0 + r;
    if (gr >= NN) break;
    float acc = bias;
    #pragma unroll
    for (int k2 = 0; k2 < 32; k2++) acc += sx[r][k2] * sW[k2 * 128 + tid];
    h[(size_t)gr * 128 + tid] = acc;
  }
  __threadfence_block();
  __syncthreads();
  int lane = tid & 63, wv = tid >> 6;
  for (int rr = 0; rr < 8; rr++){
    int r = wv * 8 + rr;
    int gr = r0 + r;
    if (gr >= NN) continue;
    const float* p = h + (size_t)gr * 128 + lane * 2;
    float x0 = p[0], x1 = p[1];
    float sum = x0 + x1;
    for (int m = 1; m < 64; m <<= 1) sum += __shfl_xor(sum, m);
    float mean = sum * (1.f / 128.f);
    float d0 = x0 - mean, d1 = x1 - mean;
    float vs = d0 * d0 + d1 * d1;
    for (int m = 1; m < 64; m <<= 1) vs += __shfl_xor(vs, m);
    float rstd = rsqrtf(vs * (1.f / 128.f) + 1e-5f);
    int d = lane * 2;
    ushort_t* o = hn + (size_t)gr * 128 + d;
    o[0] = f2us(d0 * rstd * sc[d] + bi[d]);
    o[1] = f2us(d1 * rstd * sc[d + 1] + bi[d + 1]);
  }
}

// ---------------- LayerNorm (wave per row); OUTBF16: write bf16 else fp32 ----------------
template<int OUTBF16>
__global__ void k_ln(const float* __restrict__ in, const float* __restrict__ sc,
                     const float* __restrict__ bi, void* __restrict__ outp, int rows){
  int row = blockIdx.x * 4 + (threadIdx.x >> 6);
  int lane = threadIdx.x & 63;
  if (row >= rows) return;
  const float* p = in + (size_t)row * 128 + lane * 2;
  float x0 = p[0], x1 = p[1];
  float sum = x0 + x1;
  for (int m = 1; m < 64; m <<= 1) sum += __shfl_xor(sum, m);
  float mean = sum * (1.f / 128.f);
  float d0 = x0 - mean, d1 = x1 - mean;
  float vs = d0 * d0 + d1 * d1;
  for (int m = 1; m < 64; m <<= 1) vs += __shfl_xor(vs, m);
  float rstd = rsqrtf(vs * (1.f / 128.f) + 1e-5f);
  int d = lane * 2;
  float o0 = d0 * rstd * sc[d] + bi[d];
  float o1 = d1 * rstd * sc[d + 1] + bi[d + 1];
  if (OUTBF16){
    ushort_t* o = (ushort_t*)outp + (size_t)row * 128 + d;
    o[0] = f2us(o0); o[1] = f2us(o1);
  } else {
    float* o = (float*)outp + (size_t)row * 128 + d;
    o[0] = o0; o[1] = o1;
  }
}

// ------- MFMA GEMM: C[M,N] = A[M,K](bf16) @ Bt[N,K](bf16)^T + bias -------
// MODE 1: gelu -> bf16 C (LDS epilogue)   MODE 2: C(f32) += g*(acc+bias) (direct)
// MODE 3: QKVS split -> q bf16 | kv fp8 interleaved (8B k | 8B v per 16B) | xr bf16
template<int MODE>
__global__ __launch_bounds__(256) void k_mm(const ushort_t* __restrict__ A, int M, int K,
                                            const ushort_t* __restrict__ Bt,
                                            const float* __restrict__ bias,
                                            void* __restrict__ Cp, int ldc,
                                            const float* __restrict__ gptr,
                                            ushort_t* __restrict__ qout,
                                            unsigned char* __restrict__ kvout,
                                            ushort_t* __restrict__ xrout,
                                            int nbn){
  __shared__ ushort_t smem[2 * 128 * 72];            // As | Bs, reused as Cs (128x136)
  ushort_t* As = smem;
  ushort_t* Bs = smem + 128 * 72;
  int tid = threadIdx.x;
  // bijective XCD swizzle, n fastest within each XCD chunk
  int nwg = gridDim.x;
  int orig = blockIdx.x;
  int q8 = nwg >> 3, r8 = nwg & 7;
  int xcd = orig & 7, jj = orig >> 3;
  int wgid = (xcd < r8) ? (xcd * (q8 + 1) + jj)
                        : (r8 * (q8 + 1) + (xcd - r8) * q8 + jj);
  int m0 = (wgid / nbn) * 128, n0 = (wgid % nbn) * 128;
  int lane = tid & 63, w = tid >> 6;
  int wm = (w >> 1) * 64, wn = (w & 1) * 64;
  int fr = lane & 15, fq = lane >> 4;
  f32x4 acc[4][4];
  #pragma unroll
  for (int i = 0; i < 4; i++)
    #pragma unroll
    for (int j = 0; j < 4; j++) acc[i][j] = (f32x4){0.f, 0.f, 0.f, 0.f};

  for (int k0 = 0; k0 < K; k0 += 64){
    __syncthreads();
    #pragma unroll
    for (int it = 0; it < 4; it++){
      int idx = it * 256 + tid;
      int row = idx >> 3, ks = (idx & 7) * 8;
      int gr = m0 + row; if (gr >= M) gr = M - 1;
      *(ushortx8*)&As[row * 72 + ks] = *(const ushortx8*)(A + (size_t)gr * K + k0 + ks);
      *(ushortx8*)&Bs[row * 72 + ks] = *(const ushortx8*)(Bt + (size_t)(n0 + row) * K + k0 + ks);
    }
    __syncthreads();
    #pragma unroll
    for (int ks = 0; ks < 64; ks += 32){
      s16x8 a[4], b[4];
      #pragma unroll
      for (int i = 0; i < 4; i++)
        a[i] = *(const s16x8*)&As[(wm + i * 16 + fr) * 72 + ks + fq * 8];
      #pragma unroll
      for (int j = 0; j < 4; j++)
        b[j] = *(const s16x8*)&Bs[(wn + j * 16 + fr) * 72 + ks + fq * 8];
      #pragma unroll
      for (int i = 0; i < 4; i++)
        #pragma unroll
        for (int j = 0; j < 4; j++)
          acc[i][j] = __builtin_amdgcn_mfma_f32_16x16x32_bf16(a[i], b[j], acc[i][j], 0, 0, 0);
    }
  }

  if (MODE == 2){
    float g = *gptr;
    #pragma unroll
    for (int i = 0; i < 4; i++){
      int grb = m0 + wm + i * 16 + fq * 4;
      #pragma unroll
      for (int r = 0; r < 4; r++){
        int gr = grb + r;
        if (gr >= M) continue;
        #pragma unroll
        for (int j = 0; j < 4; j++){
          int gc = n0 + wn + j * 16 + fr;
          float c = acc[i][j][r] + bias[gc];
          ((float*)Cp)[(size_t)gr * ldc + gc] += g * c;
        }
      }
    }
    return;
  }

  // ---- LDS-staged epilogue: frags -> bf16 Cs[row][col] (stride 136) -> vector stores ----
  __syncthreads();
  ushort_t* Cs = smem;
  #pragma unroll
  for (int i = 0; i < 4; i++){
    int rowb = wm + i * 16 + fq * 4;
    #pragma unroll
    for (int j = 0; j < 4; j++){
      int col = wn + j * 16 + fr;
      float bv = bias[n0 + col];
      #pragma unroll
      for (int r = 0; r < 4; r++){
        float c = acc[i][j][r] + bv;
        if (MODE == 1) c = 0.5f * c * (1.f + erff(c * 0.70710678118654752f));
        Cs[(rowb + r) * 136 + col] = f2us(c);
      }
    }
  }
  __syncthreads();
  // region is uniform per block: boundaries (512,1024,1536) are multiples of 128
  #pragma unroll
  for (int it = 0; it < 8; it++){
    int idx = it * 256 + tid;
    int row = idx >> 4, seg = idx & 15;
    int gr = m0 + row;
    if (gr >= M) continue;
    ushortx8 cv = *(const ushortx8*)&Cs[row * 136 + seg * 8];
    int gc = n0 + seg * 8;
    if (MODE == 1){
      *(ushortx8*)((ushort_t*)Cp + (size_t)gr * ldc + gc) = cv;
    } else { // MODE 3
      if (n0 < 512){
        *(ushortx8*)(qout + (size_t)gr * 512 + gc) = cv;
      } else if (n0 < 1536){
        float fv[8];
        #pragma unroll
        for (int t = 0; t < 8; t++) fv[t] = us2f(cv[t]);
        uint2 pk = f32x8_to_e4m3(fv);
        if (n0 < 1024){
          *(uint2*)(kvout + (size_t)gr * 1024 + (size_t)((gc - 512) >> 3) * 16) = pk;
        } else {
          *(uint2*)(kvout + (size_t)gr * 1024 + (size_t)((gc - 1024) >> 3) * 16 + 8) = pk;
        }
      } else {
        *(ushortx8*)(xrout + (size_t)gr * 128 + (gc - 1536)) = cv;
      }
    }
  }
}

// ---- FUSED attention: 4 nodes/block (256 thr), 16/4/1 tiers, DPP reduce ----
// Packed-pair math: dot and accumulate via f32x2 (v_pk_fma_f32); scale*log2e
// pre-folded into q; w = exp2(p) via v_exp_f32.
#define EDGE_PROC(KVD) {                                                     \
    f32x2 k01 = __builtin_amdgcn_cvt_pk_f32_fp8((KVD).x, false);             \
    f32x2 k23 = __builtin_amdgcn_cvt_pk_f32_fp8((KVD).x, true);              \
    f32x2 k45 = __builtin_amdgcn_cvt_pk_f32_fp8((KVD).y, false);             \
    f32x2 k67 = __builtin_amdgcn_cvt_pk_f32_fp8((KVD).y, true);              \
    f32x2 p2 = q01 * k01;                                                    \
    p2 = __builtin_elementwise_fma(q23, k23, p2);                            \
    p2 = __builtin_elementwise_fma(q45, k45, p2);                            \
    p2 = __builtin_elementwise_fma(q67, k67, p2);                            \
    float p = red16(p2.x + p2.y);                                            \
    float wgt = __builtin_amdgcn_exp2f(p);                                   \
    f32x2 v01 = __builtin_amdgcn_cvt_pk_f32_fp8((KVD).z, false);             \
    f32x2 v23 = __builtin_amdgcn_cvt_pk_f32_fp8((KVD).z, true);              \
    f32x2 v45 = __builtin_amdgcn_cvt_pk_f32_fp8((KVD).w, false);             \
    f32x2 v67 = __builtin_amdgcn_cvt_pk_f32_fp8((KVD).w, true);              \
    l += wgt;                                                                \
    f32x2 w2 = (f32x2){wgt, wgt};                                            \
    acc2[0] = __builtin_elementwise_fma(w2, v01, acc2[0]);                   \
    acc2[1] = __builtin_elementwise_fma(w2, v23, acc2[1]);                   \
    acc2[2] = __builtin_elementwise_fma(w2, v45, acc2[2]);                   \
    acc2[3] = __builtin_elementwise_fma(w2, v67, acc2[3]);                   \
  }

__global__ __launch_bounds__(256) void k_attn(
                       const ushort_t* __restrict__ q, const unsigned char* __restrict__ kv8,
                       const int* __restrict__ rowst, const int* __restrict__ srcs,
                       const ushort_t* __restrict__ xr, const float* __restrict__ Wb,
                       const float* __restrict__ g1p, float* __restrict__ h,
                       const float* __restrict__ sc2, const float* __restrict__ bi2,
                       ushort_t* __restrict__ hn){
  int n = blockIdx.x * 4 + (threadIdx.x >> 6);
  int lane = threadIdx.x & 63;
  if (n >= NN) return;
  int s0 = rowst[n], s1 = rowst[n + 1];
  int deg = s1 - s0;
  // q pre-scaled by scale*log2(e): exp(p*scale) == exp2(sum (q*qs)·k)
  const float qs = 0.08838834764831845f * 1.4426950408889634f;
  f32x2 q01, q23, q45, q67;
  {
    ushortx8 qv = *((const ushortx8*)(q + (size_t)n * 512) + lane);
    q01 = (f32x2){us2f(qv[0]) * qs, us2f(qv[1]) * qs};
    q23 = (f32x2){us2f(qv[2]) * qs, us2f(qv[3]) * qs};
    q45 = (f32x2){us2f(qv[4]) * qs, us2f(qv[5]) * qs};
    q67 = (f32x2){us2f(qv[6]) * qs, us2f(qv[7]) * qs};
  }
  const uint4* kvb = (const uint4*)kv8;   // 64 chunks of 16B per node record
  float l = 0.f;
  f32x2 acc2[4];
  #pragma unroll
  for (int t = 0; t < 4; t++) acc2[t] = (f32x2){0.f, 0.f};
  for (int c0 = s0; c0 < s1; c0 += 64){
    int rem = s1 - c0; if (rem > 64) rem = 64;
    int se = (lane < rem) ? srcs[c0 + lane] : 0;
    int j = 0;
    for (; j + 16 <= rem; j += 16){
      uint4 kvd[16];
      #pragma unroll
      for (int u = 0; u < 16; u++){
        int sv = __builtin_amdgcn_readlane(se, j + u);   // SGPR -> scalar base
        kvd[u] = kvb[(size_t)sv * 64 + lane];
      }
      #pragma unroll
      for (int u = 0; u < 16; u++) EDGE_PROC(kvd[u]);
    }
    for (; j + 4 <= rem; j += 4){
      uint4 kvd[4];
      #pragma unroll
      for (int u = 0; u < 4; u++){
        int sv = __builtin_amdgcn_readlane(se, j + u);
        kvd[u] = kvb[(size_t)sv * 64 + lane];
      }
      #pragma unroll
      for (int u = 0; u < 4; u++) EDGE_PROC(kvd[u]);
    }
    for (; j < rem; j++){
      int sv0 = __builtin_amdgcn_readlane(se, j);
      uint4 kvd = kvb[(size_t)sv0 * 64 + lane];
      EDGE_PROC(kvd);
    }
  }
  float inv = deg ? (0.25f / l) : 0.f;   // head-mean folded; deg==0 -> out=0
  float accs[8];
  accs[0] = acc2[0].x; accs[1] = acc2[0].y;
  accs[2] = acc2[1].x; accs[3] = acc2[1].y;
  accs[4] = acc2[2].x; accs[5] = acc2[2].y;
  accs[6] = acc2[3].x; accs[7] = acc2[3].y;
  #pragma unroll
  for (int t = 0; t < 8; t++){
    float r = accs[t] * inv;
    r += __shfl_xor(r, 16); r += __shfl_xor(r, 32);
    accs[t] = r;
  }
  // ---- epilogue on lanes 0..15: beta gate + residual + ln2 ----
  if (lane < 16){
    int d = lane * 8;
    float xv[8];
    {
      ushortx8 xrv = *(const ushortx8*)(xr + (size_t)n * 128 + d);
      #pragma unroll
      for (int t = 0; t < 8; t++) xv[t] = us2f(xrv[t]);
    }
    float pp = 0.f;
    #pragma unroll
    for (int t = 0; t < 8; t++){
      float w0 = Wb[d + t], w1 = Wb[128 + d + t], w2 = Wb[256 + d + t];
      pp += accs[t] * (w0 + w2) + xv[t] * (w1 - w2);
    }
    pp = red16(pp);
    float beta = 1.f / (1.f + __expf(-pp));
    float g = *g1p;
    float* hp = h + (size_t)n * 128 + d;
    float hv[8];
    {
      float4 h0 = *(const float4*)(hp);
      float4 h1 = *(const float4*)(hp + 4);
      hv[0]=h0.x; hv[1]=h0.y; hv[2]=h0.z; hv[3]=h0.w;
      hv[4]=h1.x; hv[5]=h1.y; hv[6]=h1.z; hv[7]=h1.w;
    }
    #pragma unroll
    for (int t = 0; t < 8; t++)
      hv[t] += g * (beta * xv[t] + (1.f - beta) * accs[t]);
    float s = 0.f;
    #pragma unroll
    for (int t = 0; t < 8; t++) s += hv[t];
    s = red16(s);
    float mean = s * (1.f / 128.f);
    float vs = 0.f;
    #pragma unroll
    for (int t = 0; t < 8; t++){ float dd = hv[t] - mean; vs += dd * dd; }
    vs = red16(vs);
    float rstd = rsqrtf(vs * (1.f / 128.f) + 1e-5f);
    *(float4*)(hp) = make_float4(hv[0], hv[1], hv[2], hv[3]);
    *(float4*)(hp + 4) = make_float4(hv[4], hv[5], hv[6], hv[7]);
    ushortx8 hno;
    #pragma unroll
    for (int t = 0; t < 8; t++)
      hno[t] = f2us((hv[t] - mean) * rstd * sc2[d + t] + bi2[d + t]);
    *(ushortx8*)(hn + (size_t)n * 128 + d) = hno;
  }
}

extern "C" void kernel_launch(void* const* d_in, const int* in_sizes, int n_in,
                              void* d_out, int out_size, void* d_ws, size_t ws_size,
                              hipStream_t stream){
  const float* x    = (const float*)d_in[0];
  const int*   ei   = (const int*)d_in[1];
  const float* Win  = (const float*)d_in[2];
  const float* bin  = (const float*)d_in[3];
  const float* ln1s = (const float*)d_in[4];
  const float* ln1b = (const float*)d_in[5];
  const float* Wq   = (const float*)d_in[6];
  const float* bq   = (const float*)d_in[7];
  const float* Wk   = (const float*)d_in[8];
  const float* bk   = (const float*)d_in[9];
  const float* Wv   = (const float*)d_in[10];
  const float* bv   = (const float*)d_in[11];
  const float* Wsk  = (const float*)d_in[12];
  const float* bsk  = (const float*)d_in[13];
  const float* Wbt  = (const float*)d_in[14];
  const float* ln2s = (const float*)d_in[15];
  const float* ln2b = (const float*)d_in[16];
  const float* W1   = (const float*)d_in[17];
  const float* b1   = (const float*)d_in[18];
  const float* W2   = (const float*)d_in[19];
  const float* b2   = (const float*)d_in[20];
  const float* g1   = (const float*)d_in[21];
  const float* g2   = (const float*)d_in[22];
  const float* lnos = (const float*)d_in[23];
  const float* lnob = (const float*)d_in[24];

  // --- workspace layout in BYTES (~88 MB; ws_size >= 170 MB established) ---
  char* wsb = (char*)d_ws;
  size_t off = 0;
  float*         h    = (float*)(wsb + off);         off += (size_t)NN * 128 * 4;
  ushort_t*      hn   = (ushort_t*)(wsb + off);      off += (size_t)NN * 128 * 2;
  ushort_t*      qbuf = (ushort_t*)(wsb + off);      off += (size_t)NN * 512 * 2;
  unsigned char* kv8  = (unsigned char*)(wsb + off); off += (size_t)NN * 1024;
  ushort_t*      xrb  = (ushort_t*)(wsb + off);      off += (size_t)NN * 128 * 2;
  ushort_t*      tb   = (ushort_t*)(wsb + off);      off += (size_t)NN * 512 * 2;
  ushort_t*      wt   = (ushort_t*)(wsb + off);      off += (size_t)688128 * 2;
  float*         bcat = (float*)(wsb + off);         off += (size_t)3328 * 4;
  int*           deg   = (int*)(wsb + off);          off += (size_t)NN * 4;
  int*           rowst = (int*)(wsb + off);          off += (size_t)(NN + 4) * 4;
  int*           rank  = (int*)(wsb + off);          off += (size_t)NE * 4;
  int*           srcs  = (int*)(wsb + off);          off += (size_t)NE * 4;
  ushort_t* Wcat = wt;                 // 2x(1664x128)
  ushort_t* W1t  = wt + 425984;        // 2x(512x128)
  ushort_t* W2t  = wt + 557056;        // 2x(128x512)

  // weights/bias/deg-zero first (deg zero precedes k_hist in stream order)
  k_wt<<<2780, 256, 0, stream>>>(Wq, Wk, Wv, Wsk, W1, W2, bq, bk, bv, bsk, wt, bcat, deg);
  k_hist<<<(NE + 255) / 256, 256, 0, stream>>>(ei, deg, rank);
  k_scan<<<1, 1024, 0, stream>>>(deg, rowst);
  k_scatter<<<(NE + 255) / 256, 256, 0, stream>>>(ei, rowst, rank, srcs);
  k_inproj<<<NN / 16, 128, 0, stream>>>(x, Win, bin, h, ln1s, ln1b, hn);

  for (int l = 0; l < 2; l++){
    if (l == 1)
      k_ln<1><<<(NN + 3) / 4, 256, 0, stream>>>(h, ln1s + 128, ln1b + 128, hn, NN);
    k_mm<3><<<157 * 13, 256, 0, stream>>>(hn, NN, 128, Wcat + (size_t)l * 212992, bcat + l * 1664,
                                          nullptr, 0, nullptr, qbuf, kv8, xrb, 13);
    k_attn<<<(NN + 3) / 4, 256, 0, stream>>>(qbuf, kv8, rowst, srcs, xrb, Wbt + l * 384,
                                             g1 + l, h, ln2s + l * 128, ln2b + l * 128, hn);
    k_mm<1><<<157 * 4, 256, 0, stream>>>(hn, NN, 128, W1t + (size_t)l * 65536, b1 + l * 512,
                                         tb, 512, nullptr, nullptr, nullptr, nullptr, 4);
    k_mm<2><<<157, 256, 0, stream>>>(tb, NN, 512, W2t + (size_t)l * 65536, b2 + l * 128,
                                     h, 128, g2 + l, nullptr, nullptr, nullptr, 1);
  }
  k_ln<0><<<(NN + 3) / 4, 256, 0, stream>>>(h, lnos, lnob, (float*)d_out, NN);
}

// Round 15
// 408.239 us; speedup vs baseline: 1.3755x; 1.0117x over previous
//
#include <hip/hip_runtime.h>
#include <hip/hip_bf16.h>
#include <math.h>

#define NN 20000
#define NE 320000

typedef unsigned short ushort_t;
typedef unsigned short ushortx8 __attribute__((ext_vector_type(8)));
typedef short s16x8 __attribute__((ext_vector_type(8)));
typedef float f32x4 __attribute__((ext_vector_type(4)));
typedef float f32x2 __attribute__((ext_vector_type(2)));

__device__ __forceinline__ float us2f(unsigned short u){
  return __uint_as_float(((unsigned)u) << 16);
}
__device__ __forceinline__ unsigned short f2us(float f){
  unsigned u = __float_as_uint(f);
  unsigned r = (u + 0x7fffu + ((u >> 16) & 1u)) >> 16;   // RNE
  return (unsigned short)r;
}
__device__ __forceinline__ void e4m3x8_to_f32(uint2 d, float* out){
  f32x2 a = __builtin_amdgcn_cvt_pk_f32_fp8(d.x, false);
  f32x2 b = __builtin_amdgcn_cvt_pk_f32_fp8(d.x, true);
  f32x2 c = __builtin_amdgcn_cvt_pk_f32_fp8(d.y, false);
  f32x2 e = __builtin_amdgcn_cvt_pk_f32_fp8(d.y, true);
  out[0] = a.x; out[1] = a.y; out[2] = b.x; out[3] = b.y;
  out[4] = c.x; out[5] = c.y; out[6] = e.x; out[7] = e.y;
}
__device__ __forceinline__ uint2 f32x8_to_e4m3(const float* f){
  unsigned lo = __builtin_amdgcn_cvt_pk_fp8_f32(f[0], f[1], 0u, false);
  lo = __builtin_amdgcn_cvt_pk_fp8_f32(f[2], f[3], lo, true);
  unsigned hi = __builtin_amdgcn_cvt_pk_fp8_f32(f[4], f[5], 0u, false);
  hi = __builtin_amdgcn_cvt_pk_fp8_f32(f[6], f[7], hi, true);
  return make_uint2(lo, hi);
}
// DPP butterfly add within 16-lane rows. Bit-identical to the shfl_xor chain.
template<int CTRL>
__device__ __forceinline__ float dpp_add(float x){
  int t = __builtin_amdgcn_update_dpp(0, __float_as_int(x), CTRL, 0xf, 0xf, true);
  return x + __int_as_float(t);
}
__device__ __forceinline__ float red16(float p){
  p = dpp_add<0xB1>(p);    // quad_perm [1,0,3,2]  == xor 1
  p = dpp_add<0x4E>(p);    // quad_perm [2,3,0,1]  == xor 2
  p = dpp_add<0x141>(p);   // row_half_mirror      == xor 4 (value-equal)
  p = dpp_add<0x140>(p);   // row_mirror           == xor 8 (value-equal)
  return p;
}

// ---------------- CSR build ----------------
// single atomic pass: rank[e] = arrival order of edge e at its dst bucket
__global__ void k_hist(const int* __restrict__ ei, int* __restrict__ deg,
                       int* __restrict__ rank){
  int e = blockIdx.x * 256 + threadIdx.x;
  if (e < NE) rank[e] = atomicAdd(&deg[ei[NE + e]], 1);
}

__global__ __launch_bounds__(1024) void k_scan(const int* __restrict__ deg,
                                               int* __restrict__ rowst){
  __shared__ int ws[16];
  int tid = threadIdx.x;
  int lane = tid & 63, wid = tid >> 6;
  int base = tid * 20;
  int v[20];
  int s = 0;
  #pragma unroll
  for (int u = 0; u < 20; u++){
    int i = base + u;
    int d = (i < NN) ? deg[i] : 0;
    v[u] = s;
    s += d;
  }
  int incl = s;
  #pragma unroll
  for (int off = 1; off < 64; off <<= 1){
    int t = __shfl_up(incl, off);
    if (lane >= off) incl += t;
  }
  if (lane == 63) ws[wid] = incl;
  __syncthreads();
  int woff = 0;
  #pragma unroll
  for (int k2 = 0; k2 < 16; k2++) if (k2 < wid) woff += ws[k2];
  int toff = woff + incl - s;
  #pragma unroll
  for (int u = 0; u < 20; u++){
    int i = base + u;
    if (i < NN) rowst[i] = toff + v[u];
  }
  if (tid == 1023) rowst[NN] = toff + s;
}

// atomic-free scatter: slot = rowst[dst] + rank
__global__ void k_scatter(const int* __restrict__ ei, const int* __restrict__ rowst,
                          const int* __restrict__ rank, int* __restrict__ srcs){
  int e = blockIdx.x * 256 + threadIdx.x;
  if (e < NE){
    int d = ei[NE + e];
    srcs[rowst[d] + rank[e]] = ei[e];
  }
}

// ------- weight convert+transpose + bias concat + deg zero (one kernel) -------
__global__ void k_wt(const float* __restrict__ Wq, const float* __restrict__ Wk,
                     const float* __restrict__ Wv, const float* __restrict__ Wsk,
                     const float* __restrict__ W1, const float* __restrict__ W2,
                     const float* __restrict__ bq, const float* __restrict__ bk,
                     const float* __restrict__ bv, const float* __restrict__ bsk,
                     ushort_t* __restrict__ out, float* __restrict__ bcat,
                     int* __restrict__ deg){
  int f = blockIdx.x * 256 + threadIdx.x;
  if (f < 688128){
    float val;
    if (f < 425984){
      int l = f / 212992, idx = f % 212992;
      int n = idx / 128, kk = idx % 128;
      if (n < 512)       val = Wq[(size_t)l * 65536 + kk * 512 + n];
      else if (n < 1024) val = Wk[(size_t)l * 65536 + kk * 512 + (n - 512)];
      else if (n < 1536) val = Wv[(size_t)l * 65536 + kk * 512 + (n - 1024)];
      else               val = Wsk[(size_t)l * 16384 + kk * 128 + (n - 1536)];
    } else if (f < 557056){
      int idx = f - 425984;
      int l = idx / 65536, r = idx % 65536;
      int n = r / 128, kk = r % 128;
      val = W1[(size_t)l * 65536 + kk * 512 + n];
    } else {
      int idx = f - 557056;
      int l = idx / 65536, r = idx % 65536;
      int n = r / 512, kk = r % 512;
      val = W2[(size_t)l * 65536 + kk * 128 + n];
    }
    out[f] = f2us(val);
  } else if (f < 691456){
    int i = f - 688128;
    int l = i / 1664, c = i % 1664;
    float v;
    if (c < 512)       v = bq[l * 512 + c];
    else if (c < 1024) v = bk[l * 512 + c - 512];
    else if (c < 1536) v = bv[l * 512 + c - 1024];
    else               v = bsk[l * 128 + c - 1536];
    bcat[i] = v;
  } else if (f < 711456){
    deg[f - 691456] = 0;
  }
}

// ------- input projection: h = x@Win + b_in (16 rows/block) + fused ln1(l=0) -------
__global__ __launch_bounds__(128) void k_inproj(const float* __restrict__ x,
                                                const float* __restrict__ Win,
                                                const float* __restrict__ bin,
                                                float* __restrict__ h,
                                                const float* __restrict__ sc,
                                                const float* __restrict__ bi,
                                                ushort_t* __restrict__ hn){
  __shared__ float sW[32 * 128];
  __shared__ float sx[16][32];
  int tid = threadIdx.x;
  for (int i = 0; i < 32; i++) sW[i * 128 + tid] = Win[i * 128 + tid];
  int r0 = blockIdx.x * 16;
  for (int rr = tid >> 5; rr < 16; rr += 4){
    int gr = r0 + rr;
    sx[rr][tid & 31] = (gr < NN) ? x[(size_t)gr * 32 + (tid & 31)] : 0.f;
  }
  __syncthreads();
  float bias = bin[tid];
  for (int r = 0; r < 16; r++){
    int gr = r0 + r;
    if (gr >= NN) break;
    float acc = bias;
    #pragma unroll
    for (int k2 = 0; k2 < 32; k2++) acc += sx[r][k2] * sW[k2 * 128 + tid];
    h[(size_t)gr * 128 + tid] = acc;
  }
  __threadfence_block();
  __syncthreads();
  int lane = tid & 63, wv = tid >> 6;
  for (int rr = 0; rr < 8; rr++){
    int r = wv * 8 + rr;
    int gr = r0 + r;
    if (gr >= NN) continue;
    const float* p = h + (size_t)gr * 128 + lane * 2;
    float x0 = p[0], x1 = p[1];
    float sum = x0 + x1;
    for (int m = 1; m < 64; m <<= 1) sum += __shfl_xor(sum, m);
    float mean = sum * (1.f / 128.f);
    float d0 = x0 - mean, d1 = x1 - mean;
    float vs = d0 * d0 + d1 * d1;
    for (int m = 1; m < 64; m <<= 1) vs += __shfl_xor(vs, m);
    float rstd = rsqrtf(vs * (1.f / 128.f) + 1e-5f);
    int d = lane * 2;
    ushort_t* o = hn + (size_t)gr * 128 + d;
    o[0] = f2us(d0 * rstd * sc[d] + bi[d]);
    o[1] = f2us(d1 * rstd * sc[d + 1] + bi[d + 1]);
  }
}

// ---------------- LayerNorm (wave per row); OUTBF16: write bf16 else fp32 ----------------
template<int OUTBF16>
__global__ void k_ln(const float* __restrict__ in, const float* __restrict__ sc,
                     const float* __restrict__ bi, void* __restrict__ outp, int rows){
  int row = blockIdx.x * 4 + (threadIdx.x >> 6);
  int lane = threadIdx.x & 63;
  if (row >= rows) return;
  const float* p = in + (size_t)row * 128 + lane * 2;
  float x0 = p[0], x1 = p[1];
  float sum = x0 + x1;
  for (int m = 1; m < 64; m <<= 1) sum += __shfl_xor(sum, m);
  float mean = sum * (1.f / 128.f);
  float d0 = x0 - mean, d1 = x1 - mean;
  float vs = d0 * d0 + d1 * d1;
  for (int m = 1; m < 64; m <<= 1) vs += __shfl_xor(vs, m);
  float rstd = rsqrtf(vs * (1.f / 128.f) + 1e-5f);
  int d = lane * 2;
  float o0 = d0 * rstd * sc[d] + bi[d];
  float o1 = d1 * rstd * sc[d + 1] + bi[d + 1];
  if (OUTBF16){
    ushort_t* o = (ushort_t*)outp + (size_t)row * 128 + d;
    o[0] = f2us(o0); o[1] = f2us(o1);
  } else {
    float* o = (float*)outp + (size_t)row * 128 + d;
    o[0] = o0; o[1] = o1;
  }
}

// ------- MFMA GEMM: C[M,N] = A[M,K](bf16) @ Bt[N,K](bf16)^T + bias -------
// MODE 1: gelu -> bf16 C (LDS epilogue)   MODE 2: C(f32) += g*(acc+bias) (direct)
// MODE 3: QKVS split -> q bf16 | kv fp8 interleaved (8B k | 8B v per 16B) | xr bf16
template<int MODE>
__global__ __launch_bounds__(256) void k_mm(const ushort_t* __restrict__ A, int M, int K,
                                            const ushort_t* __restrict__ Bt,
                                            const float* __restrict__ bias,
                                            void* __restrict__ Cp, int ldc,
                                            const float* __restrict__ gptr,
                                            ushort_t* __restrict__ qout,
                                            unsigned char* __restrict__ kvout,
                                            ushort_t* __restrict__ xrout,
                                            int nbn){
  __shared__ ushort_t smem[2 * 128 * 72];            // As | Bs, reused as Cs (128x136)
  ushort_t* As = smem;
  ushort_t* Bs = smem + 128 * 72;
  int tid = threadIdx.x;
  // bijective XCD swizzle, n fastest within each XCD chunk
  int nwg = gridDim.x;
  int orig = blockIdx.x;
  int q8 = nwg >> 3, r8 = nwg & 7;
  int xcd = orig & 7, jj = orig >> 3;
  int wgid = (xcd < r8) ? (xcd * (q8 + 1) + jj)
                        : (r8 * (q8 + 1) + (xcd - r8) * q8 + jj);
  int m0 = (wgid / nbn) * 128, n0 = (wgid % nbn) * 128;
  int lane = tid & 63, w = tid >> 6;
  int wm = (w >> 1) * 64, wn = (w & 1) * 64;
  int fr = lane & 15, fq = lane >> 4;
  f32x4 acc[4][4];
  #pragma unroll
  for (int i = 0; i < 4; i++)
    #pragma unroll
    for (int j = 0; j < 4; j++) acc[i][j] = (f32x4){0.f, 0.f, 0.f, 0.f};

  for (int k0 = 0; k0 < K; k0 += 64){
    __syncthreads();
    #pragma unroll
    for (int it = 0; it < 4; it++){
      int idx = it * 256 + tid;
      int row = idx >> 3, ks = (idx & 7) * 8;
      int gr = m0 + row; if (gr >= M) gr = M - 1;
      *(ushortx8*)&As[row * 72 + ks] = *(const ushortx8*)(A + (size_t)gr * K + k0 + ks);
      *(ushortx8*)&Bs[row * 72 + ks] = *(const ushortx8*)(Bt + (size_t)(n0 + row) * K + k0 + ks);
    }
    __syncthreads();
    #pragma unroll
    for (int ks = 0; ks < 64; ks += 32){
      s16x8 a[4], b[4];
      #pragma unroll
      for (int i = 0; i < 4; i++)
        a[i] = *(const s16x8*)&As[(wm + i * 16 + fr) * 72 + ks + fq * 8];
      #pragma unroll
      for (int j = 0; j < 4; j++)
        b[j] = *(const s16x8*)&Bs[(wn + j * 16 + fr) * 72 + ks + fq * 8];
      #pragma unroll
      for (int i = 0; i < 4; i++)
        #pragma unroll
        for (int j = 0; j < 4; j++)
          acc[i][j] = __builtin_amdgcn_mfma_f32_16x16x32_bf16(a[i], b[j], acc[i][j], 0, 0, 0);
    }
  }

  if (MODE == 2){
    float g = *gptr;
    #pragma unroll
    for (int i = 0; i < 4; i++){
      int grb = m0 + wm + i * 16 + fq * 4;
      #pragma unroll
      for (int r = 0; r < 4; r++){
        int gr = grb + r;
        if (gr >= M) continue;
        #pragma unroll
        for (int j = 0; j < 4; j++){
          int gc = n0 + wn + j * 16 + fr;
          float c = acc[i][j][r] + bias[gc];
          ((float*)Cp)[(size_t)gr * ldc + gc] += g * c;
        }
      }
    }
    return;
  }

  // ---- LDS-staged epilogue: frags -> bf16 Cs[row][col] (stride 136) -> vector stores ----
  __syncthreads();
  ushort_t* Cs = smem;
  #pragma unroll
  for (int i = 0; i < 4; i++){
    int rowb = wm + i * 16 + fq * 4;
    #pragma unroll
    for (int j = 0; j < 4; j++){
      int col = wn + j * 16 + fr;
      float bv = bias[n0 + col];
      #pragma unroll
      for (int r = 0; r < 4; r++){
        float c = acc[i][j][r] + bv;
        if (MODE == 1) c = 0.5f * c * (1.f + erff(c * 0.70710678118654752f));
        Cs[(rowb + r) * 136 + col] = f2us(c);
      }
    }
  }
  __syncthreads();
  // region is uniform per block: boundaries (512,1024,1536) are multiples of 128
  #pragma unroll
  for (int it = 0; it < 8; it++){
    int idx = it * 256 + tid;
    int row = idx >> 4, seg = idx & 15;
    int gr = m0 + row;
    if (gr >= M) continue;
    ushortx8 cv = *(const ushortx8*)&Cs[row * 136 + seg * 8];
    int gc = n0 + seg * 8;
    if (MODE == 1){
      *(ushortx8*)((ushort_t*)Cp + (size_t)gr * ldc + gc) = cv;
    } else { // MODE 3
      if (n0 < 512){
        *(ushortx8*)(qout + (size_t)gr * 512 + gc) = cv;
      } else if (n0 < 1536){
        float fv[8];
        #pragma unroll
        for (int t = 0; t < 8; t++) fv[t] = us2f(cv[t]);
        uint2 pk = f32x8_to_e4m3(fv);
        if (n0 < 1024){
          *(uint2*)(kvout + (size_t)gr * 1024 + (size_t)((gc - 512) >> 3) * 16) = pk;
        } else {
          *(uint2*)(kvout + (size_t)gr * 1024 + (size_t)((gc - 1024) >> 3) * 16 + 8) = pk;
        }
      } else {
        *(ushortx8*)(xrout + (size_t)gr * 128 + (gc - 1536)) = cv;
      }
    }
  }
}

// ---- FUSED attention: 4 nodes/block (256 thr), 12/4/1 tiers, DPP reduce ----
// Packed-pair math: dot and accumulate via f32x2 (v_pk_fma_f32); scale*log2e
// pre-folded into q; w = exp2(p) via v_exp_f32.
#define EDGE_PROC(KVD) {                                                     \
    f32x2 k01 = __builtin_amdgcn_cvt_pk_f32_fp8((KVD).x, false);             \
    f32x2 k23 = __builtin_amdgcn_cvt_pk_f32_fp8((KVD).x, true);              \
    f32x2 k45 = __builtin_amdgcn_cvt_pk_f32_fp8((KVD).y, false);             \
    f32x2 k67 = __builtin_amdgcn_cvt_pk_f32_fp8((KVD).y, true);              \
    f32x2 p2 = q01 * k01;                                                    \
    p2 = __builtin_elementwise_fma(q23, k23, p2);                            \
    p2 = __builtin_elementwise_fma(q45, k45, p2);                            \
    p2 = __builtin_elementwise_fma(q67, k67, p2);                            \
    float p = red16(p2.x + p2.y);                                            \
    float wgt = __builtin_amdgcn_exp2f(p);                                   \
    f32x2 v01 = __builtin_amdgcn_cvt_pk_f32_fp8((KVD).z, false);             \
    f32x2 v23 = __builtin_amdgcn_cvt_pk_f32_fp8((KVD).z, true);              \
    f32x2 v45 = __builtin_amdgcn_cvt_pk_f32_fp8((KVD).w, false);             \
    f32x2 v67 = __builtin_amdgcn_cvt_pk_f32_fp8((KVD).w, true);              \
    l += wgt;                                                                \
    f32x2 w2 = (f32x2){wgt, wgt};                                            \
    acc2[0] = __builtin_elementwise_fma(w2, v01, acc2[0]);                   \
    acc2[1] = __builtin_elementwise_fma(w2, v23, acc2[1]);                   \
    acc2[2] = __builtin_elementwise_fma(w2, v45, acc2[2]);                   \
    acc2[3] = __builtin_elementwise_fma(w2, v67, acc2[3]);                   \
  }

__global__ __launch_bounds__(256) void k_attn(
                       const ushort_t* __restrict__ q, const unsigned char* __restrict__ kv8,
                       const int* __restrict__ rowst, const int* __restrict__ srcs,
                       const ushort_t* __restrict__ xr, const float* __restrict__ Wb,
                       const float* __restrict__ g1p, float* __restrict__ h,
                       const float* __restrict__ sc2, const float* __restrict__ bi2,
                       ushort_t* __restrict__ hn){
  int n = blockIdx.x * 4 + (threadIdx.x >> 6);
  int lane = threadIdx.x & 63;
  if (n >= NN) return;
  int s0 = rowst[n], s1 = rowst[n + 1];
  int deg = s1 - s0;
  // q pre-scaled by scale*log2(e): exp(p*scale) == exp2(sum (q*qs)·k)
  const float qs = 0.08838834764831845f * 1.4426950408889634f;
  f32x2 q01, q23, q45, q67;
  {
    ushortx8 qv = *((const ushortx8*)(q + (size_t)n * 512) + lane);
    q01 = (f32x2){us2f(qv[0]) * qs, us2f(qv[1]) * qs};
    q23 = (f32x2){us2f(qv[2]) * qs, us2f(qv[3]) * qs};
    q45 = (f32x2){us2f(qv[4]) * qs, us2f(qv[5]) * qs};
    q67 = (f32x2){us2f(qv[6]) * qs, us2f(qv[7]) * qs};
  }
  const uint4* kvb = (const uint4*)kv8;   // 64 chunks of 16B per node record
  float l = 0.f;
  f32x2 acc2[4];
  #pragma unroll
  for (int t = 0; t < 4; t++) acc2[t] = (f32x2){0.f, 0.f};
  for (int c0 = s0; c0 < s1; c0 += 64){
    int rem = s1 - c0; if (rem > 64) rem = 64;
    int se = (lane < rem) ? srcs[c0 + lane] : 0;
    int j = 0;
    for (; j + 12 <= rem; j += 12){
      uint4 kvd[12];
      #pragma unroll
      for (int u = 0; u < 12; u++){
        int sv = __builtin_amdgcn_readlane(se, j + u);   // SGPR -> scalar base
        kvd[u] = kvb[(size_t)sv * 64 + lane];
      }
      #pragma unroll
      for (int u = 0; u < 12; u++) EDGE_PROC(kvd[u]);
    }
    for (; j + 4 <= rem; j += 4){
      uint4 kvd[4];
      #pragma unroll
      for (int u = 0; u < 4; u++){
        int sv = __builtin_amdgcn_readlane(se, j + u);
        kvd[u] = kvb[(size_t)sv * 64 + lane];
      }
      #pragma unroll
      for (int u = 0; u < 4; u++) EDGE_PROC(kvd[u]);
    }
    for (; j < rem; j++){
      int sv0 = __builtin_amdgcn_readlane(se, j);
      uint4 kvd = kvb[(size_t)sv0 * 64 + lane];
      EDGE_PROC(kvd);
    }
  }
  float inv = deg ? (0.25f / l) : 0.f;   // head-mean folded; deg==0 -> out=0
  float accs[8];
  accs[0] = acc2[0].x; accs[1] = acc2[0].y;
  accs[2] = acc2[1].x; accs[3] = acc2[1].y;
  accs[4] = acc2[2].x; accs[5] = acc2[2].y;
  accs[6] = acc2[3].x; accs[7] = acc2[3].y;
  #pragma unroll
  for (int t = 0; t < 8; t++){
    float r = accs[t] * inv;
    r += __shfl_xor(r, 16); r += __shfl_xor(r, 32);
    accs[t] = r;
  }
  // ---- epilogue on lanes 0..15: beta gate + residual + ln2 ----
  if (lane < 16){
    int d = lane * 8;
    float xv[8];
    {
      ushortx8 xrv = *(const ushortx8*)(xr + (size_t)n * 128 + d);
      #pragma unroll
      for (int t = 0; t < 8; t++) xv[t] = us2f(xrv[t]);
    }
    float pp = 0.f;
    #pragma unroll
    for (int t = 0; t < 8; t++){
      float w0 = Wb[d + t], w1 = Wb[128 + d + t], w2 = Wb[256 + d + t];
      pp += accs[t] * (w0 + w2) + xv[t] * (w1 - w2);
    }
    pp = red16(pp);
    float beta = 1.f / (1.f + __expf(-pp));
    float g = *g1p;
    float* hp = h + (size_t)n * 128 + d;
    float hv[8];
    {
      float4 h0 = *(const float4*)(hp);
      float4 h1 = *(const float4*)(hp + 4);
      hv[0]=h0.x; hv[1]=h0.y; hv[2]=h0.z; hv[3]=h0.w;
      hv[4]=h1.x; hv[5]=h1.y; hv[6]=h1.z; hv[7]=h1.w;
    }
    #pragma unroll
    for (int t = 0; t < 8; t++)
      hv[t] += g * (beta * xv[t] + (1.f - beta) * accs[t]);
    float s = 0.f;
    #pragma unroll
    for (int t = 0; t < 8; t++) s += hv[t];
    s = red16(s);
    float mean = s * (1.f / 128.f);
    float vs = 0.f;
    #pragma unroll
    for (int t = 0; t < 8; t++){ float dd = hv[t] - mean; vs += dd * dd; }
    vs = red16(vs);
    float rstd = rsqrtf(vs * (1.f / 128.f) + 1e-5f);
    *(float4*)(hp) = make_float4(hv[0], hv[1], hv[2], hv[3]);
    *(float4*)(hp + 4) = make_float4(hv[4], hv[5], hv[6], hv[7]);
    ushortx8 hno;
    #pragma unroll
    for (int t = 0; t < 8; t++)
      hno[t] = f2us((hv[t] - mean) * rstd * sc2[d + t] + bi2[d + t]);
    *(ushortx8*)(hn + (size_t)n * 128 + d) = hno;
  }
}

extern "C" void kernel_launch(void* const* d_in, const int* in_sizes, int n_in,
                              void* d_out, int out_size, void* d_ws, size_t ws_size,
                              hipStream_t stream){
  const float* x    = (const float*)d_in[0];
  const int*   ei   = (const int*)d_in[1];
  const float* Win  = (const float*)d_in[2];
  const float* bin  = (const float*)d_in[3];
  const float* ln1s = (const float*)d_in[4];
  const float* ln1b = (const float*)d_in[5];
  const float* Wq   = (const float*)d_in[6];
  const float* bq   = (const float*)d_in[7];
  const float* Wk   = (const float*)d_in[8];
  const float* bk   = (const float*)d_in[9];
  const float* Wv   = (const float*)d_in[10];
  const float* bv   = (const float*)d_in[11];
  const float* Wsk  = (const float*)d_in[12];
  const float* bsk  = (const float*)d_in[13];
  const float* Wbt  = (const float*)d_in[14];
  const float* ln2s = (const float*)d_in[15];
  const float* ln2b = (const float*)d_in[16];
  const float* W1   = (const float*)d_in[17];
  const float* b1   = (const float*)d_in[18];
  const float* W2   = (const float*)d_in[19];
  const float* b2   = (const float*)d_in[20];
  const float* g1   = (const float*)d_in[21];
  const float* g2   = (const float*)d_in[22];
  const float* lnos = (const float*)d_in[23];
  const float* lnob = (const float*)d_in[24];

  // --- workspace layout in BYTES (~88 MB; ws_size >= 170 MB established) ---
  char* wsb = (char*)d_ws;
  size_t off = 0;
  float*         h    = (float*)(wsb + off);         off += (size_t)NN * 128 * 4;
  ushort_t*      hn   = (ushort_t*)(wsb + off);      off += (size_t)NN * 128 * 2;
  ushort_t*      qbuf = (ushort_t*)(wsb + off);      off += (size_t)NN * 512 * 2;
  unsigned char* kv8  = (unsigned char*)(wsb + off); off += (size_t)NN * 1024;
  ushort_t*      xrb  = (ushort_t*)(wsb + off);      off += (size_t)NN * 128 * 2;
  ushort_t*      tb   = (ushort_t*)(wsb + off);      off += (size_t)NN * 512 * 2;
  ushort_t*      wt   = (ushort_t*)(wsb + off);      off += (size_t)688128 * 2;
  float*         bcat = (float*)(wsb + off);         off += (size_t)3328 * 4;
  int*           deg   = (int*)(wsb + off);          off += (size_t)NN * 4;
  int*           rowst = (int*)(wsb + off);          off += (size_t)(NN + 4) * 4;
  int*           rank  = (int*)(wsb + off);          off += (size_t)NE * 4;
  int*           srcs  = (int*)(wsb + off);          off += (size_t)NE * 4;
  ushort_t* Wcat = wt;                 // 2x(1664x128)
  ushort_t* W1t  = wt + 425984;        // 2x(512x128)
  ushort_t* W2t  = wt + 557056;        // 2x(128x512)

  // weights/bias/deg-zero first (deg zero precedes k_hist in stream order)
  k_wt<<<2780, 256, 0, stream>>>(Wq, Wk, Wv, Wsk, W1, W2, bq, bk, bv, bsk, wt, bcat, deg);
  k_hist<<<(NE + 255) / 256, 256, 0, stream>>>(ei, deg, rank);
  k_scan<<<1, 1024, 0, stream>>>(deg, rowst);
  k_scatter<<<(NE + 255) / 256, 256, 0, stream>>>(ei, rowst, rank, srcs);
  k_inproj<<<NN / 16, 128, 0, stream>>>(x, Win, bin, h, ln1s, ln1b, hn);

  for (int l = 0; l < 2; l++){
    if (l == 1)
      k_ln<1><<<(NN + 3) / 4, 256, 0, stream>>>(h, ln1s + 128, ln1b + 128, hn, NN);
    k_mm<3><<<157 * 13, 256, 0, stream>>>(hn, NN, 128, Wcat + (size_t)l * 212992, bcat + l * 1664,
                                          nullptr, 0, nullptr, qbuf, kv8, xrb, 13);
    k_attn<<<(NN + 3) / 4, 256, 0, stream>>>(qbuf, kv8, rowst, srcs, xrb, Wbt + l * 384,
                                             g1 + l, h, ln2s + l * 128, ln2b + l * 128, hn);
    k_mm<1><<<157 * 4, 256, 0, stream>>>(hn, NN, 128, W1t + (size_t)l * 65536, b1 + l * 512,
                                         tb, 512, nullptr, nullptr, nullptr, nullptr, 4);
    k_mm<2><<<157, 256, 0, stream>>>(tb, NN, 512, W2t + (size_t)l * 65536, b2 + l * 128,
                                     h, 128, g2 + l, nullptr, nullptr, nullptr, 1);
  }
  k_ln<0><<<(NN + 3) / 4, 256, 0, stream>>>(h, lnos, lnob, (float*)d_out, NN);
}